// Round 7
// baseline (880.168 us; speedup 1.0000x reference)
//
#include <hip/hip_runtime.h>
#include <math.h>

#define N_NODES 20000
#define N_PAD   20096            // 157 * 128
#define N_EDGES 100000
#define N_GRAPHS 64
#define IN_F 63
#define NHEAD 8
#define F 1024                   // NHEAD * HID
#define NCLS 18
#define BN_EPS 1e-5f
#define BN_CHUNKS 256

typedef __attribute__((ext_vector_type(8))) _Float16 half8v;  // 8 f16 (4 VGPRs)
typedef __attribute__((ext_vector_type(4))) _Float16 half4v;
typedef __attribute__((ext_vector_type(4))) float f32x4;

// ---------------- utility kernels ----------------
__global__ void k_zero_i32(int* __restrict__ p, int n) {
    int i = blockIdx.x * blockDim.x + threadIdx.x;
    if (i < n) p[i] = 0;
}

__global__ void k_copy_i32(int* __restrict__ d, const int* __restrict__ s, int n) {
    int i = blockIdx.x * blockDim.x + threadIdx.x;
    if (i < n) d[i] = s[i];
}

// ---------------- CSR build over dst ----------------
__global__ void k_count(const int* __restrict__ dst, int* __restrict__ cnt) {
    int i = blockIdx.x * blockDim.x + threadIdx.x;
    if (i < N_EDGES) atomicAdd(&cnt[dst[i]], 1);
}

__global__ void k_scan(const int* __restrict__ cnt, int* __restrict__ off) {
    __shared__ int tsum[256];
    const int CH = (N_NODES + 255) / 256;
    int t = threadIdx.x;
    int s = 0;
    for (int i = 0; i < CH; ++i) {
        int idx = t * CH + i;
        if (idx < N_NODES) s += cnt[idx];
    }
    tsum[t] = s;
    __syncthreads();
    if (t == 0) {
        int acc = 0;
        for (int i = 0; i < 256; ++i) { int v = tsum[i]; tsum[i] = acc; acc += v; }
    }
    __syncthreads();
    int run = tsum[t];
    for (int i = 0; i < CH; ++i) {
        int idx = t * CH + i;
        if (idx < N_NODES) { off[idx] = run; run += cnt[idx]; }
    }
    if (t == 255) off[N_NODES] = run;
}

__global__ void k_fill(const int* __restrict__ dst, int* __restrict__ cursor,
                       int* __restrict__ csr_e) {
    int i = blockIdx.x * blockDim.x + threadIdx.x;
    if (i < N_EDGES) {
        int p = atomicAdd(&cursor[dst[i]], 1);
        csr_e[p] = i;
    }
}

__global__ void k_sort_buckets(const int* __restrict__ off, int* __restrict__ csr_e) {
    int n = blockIdx.x * blockDim.x + threadIdx.x;
    if (n >= N_NODES) return;
    int b = off[n], e = off[n + 1];
    for (int i = b + 1; i < e; ++i) {
        int v = csr_e[i];
        int j = i - 1;
        while (j >= b && csr_e[j] > v) { csr_e[j + 1] = csr_e[j]; --j; }
        csr_e[j + 1] = v;
    }
}

__global__ void k_gstart(const int* __restrict__ gid, int* __restrict__ gstart) {
    int g = blockIdx.x * blockDim.x + threadIdx.x;
    if (g > N_GRAPHS) return;
    int lo = 0, hi = N_NODES;
    while (lo < hi) {
        int mid = (lo + hi) >> 1;
        if (gid[mid] < g) lo = mid + 1; else hi = mid;
    }
    gstart[g] = lo;
}

// ---------------- conversions for f16 GEMM ----------------
__global__ void k_cvt_h(const float* __restrict__ h, _Float16* __restrict__ xh) {
    int idx = blockIdx.x * 256 + threadIdx.x;
    if (idx >= N_PAD * 64) return;
    int m = idx >> 6, k = idx & 63;
    float v = (m < N_NODES && k < IN_F) ? h[m * IN_F + k] : 0.f;
    xh[idx] = (_Float16)v;
}

__global__ void k_zero_pad(_Float16* __restrict__ xh) {
    int idx = blockIdx.x * 256 + threadIdx.x;
    const int total = (N_PAD - N_NODES) * F;
    if (idx < total) xh[(size_t)N_NODES * F + idx] = (_Float16)0.f;
}

// W [K][1024] f32 -> W^T [1024][Kpad] f16; two matrices per launch (grid.z)
__global__ void k_cvt_w2(const float* __restrict__ W0, _Float16* __restrict__ o0,
                         const float* __restrict__ W1, _Float16* __restrict__ o1,
                         int K, int Kpad) {
    const float* W = blockIdx.z ? W1 : W0;
    _Float16* wh = blockIdx.z ? o1 : o0;
    __shared__ float t[32][33];
    int kt = blockIdx.x * 32, nt = blockIdx.y * 32;
    int tx = threadIdx.x & 31, ty = threadIdx.x >> 5;
#pragma unroll
    for (int j = 0; j < 4; ++j) {
        int k = kt + ty + j * 8;
        t[ty + j * 8][tx] = (k < K) ? W[(size_t)k * F + nt + tx] : 0.f;
    }
    __syncthreads();
#pragma unroll
    for (int j = 0; j < 4; ++j) {
        int n = nt + ty + j * 8;
        wh[(size_t)n * Kpad + kt + tx] = (_Float16)t[tx][ty + j * 8];
    }
}

// ---------------- fused dual f16 MFMA GEMM: 2-phase, B-only dbuf LDS ----------------
// A fragments read direct global->VGPR (coalesced 64B-line pattern, L2/L3-served).
// B (Ws^T, Wd^T) double-buffered in LDS with XOR swizzle (rule 21, both sides).
// Loop: {A-regs (issued first), stage next-B, MFMA (vmcnt leaves stage in flight),
// one barrier}. grid = (8, N_PAD/128), 256 threads.
#define AS1C(p) ((const __attribute__((address_space(1))) void*)(p))
#define AS3(p)  ((__attribute__((address_space(3))) void*)(p))

__launch_bounds__(256, 2)
__global__ void k_gemm_dual(const _Float16* __restrict__ A,
                            const _Float16* __restrict__ Bs, const _Float16* __restrict__ Bd,
                            const float* __restrict__ bias_s, const float* __restrict__ bias_d,
                            _Float16* __restrict__ Cs, _Float16* __restrict__ Cd, int Kpad) {
    __shared__ _Float16 lds[2][2][128 * 64];   // [buf][s/d][128][64] f16 = 64 KiB
    const int l = threadIdx.x & 63, w = threadIdx.x >> 6;

    // XCD-aware bijective swizzle: nwg = 8*157 = 1256, 1256 % 8 == 0
    const int orig = blockIdx.y * 8 + blockIdx.x;
    const int wg = (orig & 7) * (N_PAD / 128) + (orig >> 3);
    const int by = wg >> 3, bx = wg & 7;

    // --- B staging: wave w stages rows [w*32, w*32+32) of each B tile ---
    const int grow = w * 32 + (l >> 3);
    const int gcol = ((l & 7) ^ (l >> 3)) << 3;         // swizzled 16B chunk (halves)
    const size_t rstep = (size_t)8 * Kpad;
    const _Float16* gBs = Bs + (size_t)(bx * 128 + grow) * Kpad + gcol;
    const _Float16* gBd = Bd + (size_t)(bx * 128 + grow) * Kpad + gcol;

    // --- fragment coords: wave (wr,wc) owns a 64x64 sub-tile of each output ---
    const int wr = (w >> 1) * 64, wc = (w & 1) * 64;
    const int frow = l & 15;
    const int swz = (l & 7) << 4;                       // read-side XOR (row&7 == l&7)
    const int kbase = (l >> 4) * 16;                    // byte offset of k-chunk

    // --- A direct fragment base: row = by*128 + wr + mi*16 + (l&15), k-chunk (l>>4)*8 ---
    const _Float16* pA = A + (size_t)(by * 128 + wr + frow) * Kpad + (l >> 4) * 8;

    f32x4 accS[4][4], accD[4][4];
    const f32x4 fzero = {0.f, 0.f, 0.f, 0.f};
#pragma unroll
    for (int i = 0; i < 4; ++i)
#pragma unroll
        for (int j = 0; j < 4; ++j) { accS[i][j] = fzero; accD[i][j] = fzero; }

    auto stage = [&](int b, int k0) {
        char* ds = (char*)&lds[b][0][0] + w * 4096;
        char* dd = (char*)&lds[b][1][0] + w * 4096;
#pragma unroll
        for (int j = 0; j < 4; ++j) {
            __builtin_amdgcn_global_load_lds(AS1C(gBs + k0 + j * rstep), AS3(ds + j * 1024), 16, 0, 0);
            __builtin_amdgcn_global_load_lds(AS1C(gBd + k0 + j * rstep), AS3(dd + j * 1024), 16, 0, 0);
        }
    };

    stage(0, 0);
    __syncthreads();

    int buf = 0;
    for (int k0 = 0; k0 < Kpad; k0 += 64) {
        // A fragments for this step (issued before stage so their waitcnt
        // leaves the 8 stage loads in flight during the MFMAs)
        half8v a[4][2];
#pragma unroll
        for (int mi = 0; mi < 4; ++mi)
#pragma unroll
            for (int kk = 0; kk < 2; ++kk)
                a[mi][kk] = *(const half8v*)(pA + (size_t)mi * 16 * Kpad + k0 + kk * 32);

        if (k0 + 64 < Kpad) stage(buf ^ 1, k0 + 64);

        const char* lbs = (const char*)&lds[buf][0][0];
        const char* lbd = (const char*)&lds[buf][1][0];
#pragma unroll
        for (int kk = 0; kk < 2; ++kk) {
            const int kb = (kk * 64 + kbase) ^ swz;
#pragma unroll
            for (int ni = 0; ni < 4; ++ni) {
                int rowb = wc + ni * 16 + frow;
                half8v bs = *(const half8v*)(lbs + rowb * 128 + kb);
                half8v bd = *(const half8v*)(lbd + rowb * 128 + kb);
#pragma unroll
                for (int mi = 0; mi < 4; ++mi) {
                    accS[mi][ni] = __builtin_amdgcn_mfma_f32_16x16x32_f16(a[mi][kk], bs, accS[mi][ni], 0, 0, 0);
                    accD[mi][ni] = __builtin_amdgcn_mfma_f32_16x16x32_f16(a[mi][kk], bd, accD[mi][ni], 0, 0, 0);
                }
            }
        }
        __syncthreads();   // drains this iter's stage (landed during MFMAs)
        buf ^= 1;
    }

    // epilogue: C/D layout col = lane&15, row = (lane>>4)*4 + reg; f16 stores
    const int crow0 = by * 128 + wr + (l >> 4) * 4;
    const int ccol = bx * 128 + wc + (l & 15);
    float bS[4], bD[4];
#pragma unroll
    for (int ni = 0; ni < 4; ++ni) { bS[ni] = bias_s[ccol + ni * 16]; bD[ni] = bias_d[ccol + ni * 16]; }
#pragma unroll
    for (int mi = 0; mi < 4; ++mi) {
#pragma unroll
        for (int r = 0; r < 4; ++r) {
            int row = crow0 + mi * 16 + r;
            if (row < N_NODES) {
#pragma unroll
                for (int ni = 0; ni < 4; ++ni) {
                    int col = ccol + ni * 16;
                    Cs[(size_t)row * F + col] = (_Float16)(accS[mi][ni][r] + bS[ni]);
                    Cd[(size_t)row * F + col] = (_Float16)(accD[mi][ni][r] + bD[ni]);
                }
            }
        }
    }
}

// ---------------- fused GATv2 edge+softmax+aggregate (online softmax, f16 io) ----------------
__launch_bounds__(256)
__global__ void k_gat(const _Float16* __restrict__ fs, const _Float16* __restrict__ fd,
                      const int* __restrict__ off, const int* __restrict__ csr_e,
                      const int* __restrict__ src, const float* __restrict__ attn,
                      const float* __restrict__ bias, _Float16* __restrict__ y16) {
    __shared__ int s_src[256];
    const int n = blockIdx.x;
    const int t = threadIdx.x;
    const int b = off[n], e = off[n + 1];

    half4v fdv = *(const half4v*)(fd + (size_t)n * F + t * 4);
    const float fd0 = (float)fdv.x, fd1 = (float)fdv.y, fd2 = (float)fdv.z, fd3 = (float)fdv.w;
    const float4 av = *(const float4*)(attn + (t >> 5) * 128 + (t & 31) * 4);

    float m = -1e30f, den = 0.f;
    float ax = 0.f, ay = 0.f, az = 0.f, aw = 0.f;

    for (int c0 = b; c0 < e; c0 += 256) {
        int ncur = e - c0; if (ncur > 256) ncur = 256;
        __syncthreads();
        if (t < ncur) s_src[t] = src[csr_e[c0 + t]];
        __syncthreads();
        for (int i = 0; i < ncur; ++i) {
            int s = s_src[i];
            half4v fsv = *(const half4v*)(fs + (size_t)s * F + t * 4);
            float f0 = (float)fsv.x, f1 = (float)fsv.y, f2 = (float)fsv.z, f3 = (float)fsv.w;
            float vx = f0 + fd0; vx = vx > 0.f ? vx : 0.2f * vx;
            float vy = f1 + fd1; vy = vy > 0.f ? vy : 0.2f * vy;
            float vz = f2 + fd2; vz = vz > 0.f ? vz : 0.2f * vz;
            float vw = f3 + fd3; vw = vw > 0.f ? vw : 0.2f * vw;
            float p = vx * av.x + vy * av.y + vz * av.z + vw * av.w;
            p += __shfl_xor(p, 1);
            p += __shfl_xor(p, 2);
            p += __shfl_xor(p, 4);
            p += __shfl_xor(p, 8);
            p += __shfl_xor(p, 16);
            float mn = fmaxf(m, p);
            float so = __expf(m - mn);
            float wexp = __expf(p - mn);
            den = den * so + wexp;
            ax = ax * so + wexp * f0;
            ay = ay * so + wexp * f1;
            az = az * so + wexp * f2;
            aw = aw * so + wexp * f3;
            m = mn;
        }
    }
    float inv = (e > b) ? 1.f / den : 0.f;
    const float4 bb = *(const float4*)(bias + t * 4);
    half4v o;
    o.x = (_Float16)(ax * inv + bb.x);
    o.y = (_Float16)(ay * inv + bb.y);
    o.z = (_Float16)(az * inv + bb.z);
    o.w = (_Float16)(aw * inv + bb.w);
    *(half4v*)(y16 + (size_t)n * F + t * 4) = o;
}

// ---------------- BatchNorm (2-stage deterministic) + lrelu, f16 y ----------------
__global__ void k_bnpart(const _Float16* __restrict__ y16, float* __restrict__ part) {
    const int ROWS = (N_NODES + BN_CHUNKS - 1) / BN_CHUNKS;
    int blk = blockIdx.x;
    int t = threadIdx.x;
    int r0 = blk * ROWS;
    int r1 = r0 + ROWS; if (r1 > N_NODES) r1 = N_NODES;
    float sx = 0.f, sy = 0.f, sz = 0.f, sw = 0.f;
    float qx = 0.f, qy = 0.f, qz = 0.f, qw = 0.f;
    for (int r = r0; r < r1; ++r) {
        half4v v = *(const half4v*)(y16 + (size_t)r * F + t * 4);
        float vx = (float)v.x, vy = (float)v.y, vz = (float)v.z, vw = (float)v.w;
        sx += vx; sy += vy; sz += vz; sw += vw;
        qx += vx * vx; qy += vy * vy; qz += vz * vz; qw += vw * vw;
    }
    float4 s4; s4.x = sx; s4.y = sy; s4.z = sz; s4.w = sw;
    float4 q4; q4.x = qx; q4.y = qy; q4.z = qz; q4.w = qw;
    *(float4*)(part + (size_t)blk * (2 * F) + t * 4) = s4;
    *(float4*)(part + (size_t)blk * (2 * F) + F + t * 4) = q4;
}

__global__ void k_bnfin(const float* __restrict__ part, const float* __restrict__ gamma,
                        const float* __restrict__ beta, float* __restrict__ scale,
                        float* __restrict__ shift) {
    int c = blockIdx.x * blockDim.x + threadIdx.x;
    if (c >= F) return;
    float s = 0.f, q = 0.f;
    for (int b = 0; b < BN_CHUNKS; ++b) {
        s += part[(size_t)b * (2 * F) + c];
        q += part[(size_t)b * (2 * F) + F + c];
    }
    float mu = s / (float)N_NODES;
    float var = q / (float)N_NODES - mu * mu;
    float sc = gamma[c] * rsqrtf(var + BN_EPS);
    scale[c] = sc;
    shift[c] = beta[c] - mu * sc;
}

// BN+lrelu from f16 y; mode 0: emit f16 xh (layers 1,2); mode 1: emit f32 x (layer 3)
__global__ void k_bnapply(const _Float16* __restrict__ y16, const float* __restrict__ scale,
                          const float* __restrict__ shift, float* __restrict__ x,
                          _Float16* __restrict__ xh, int mode) {
    int i = blockIdx.x * blockDim.x + threadIdx.x;
    if (i >= N_NODES * (F / 4)) return;
    int c4 = (i & (F / 4 - 1)) * 4;
    half4v v = ((const half4v*)y16)[i];
    float4 o;
    o.x = (float)v.x * scale[c4 + 0] + shift[c4 + 0];
    o.y = (float)v.y * scale[c4 + 1] + shift[c4 + 1];
    o.z = (float)v.z * scale[c4 + 2] + shift[c4 + 2];
    o.w = (float)v.w * scale[c4 + 3] + shift[c4 + 3];
    o.x = o.x > 0.f ? o.x : 0.01f * o.x;
    o.y = o.y > 0.f ? o.y : 0.01f * o.y;
    o.z = o.z > 0.f ? o.z : 0.01f * o.z;
    o.w = o.w > 0.f ? o.w : 0.01f * o.w;
    if (mode == 0) {
        half4v h4;
        h4.x = (_Float16)o.x; h4.y = (_Float16)o.y;
        h4.z = (_Float16)o.z; h4.w = (_Float16)o.w;
        *(half4v*)&xh[(size_t)i * 4] = h4;
    } else {
        ((float4*)x)[i] = o;
    }
}

// ---------------- avg pool per graph -> f16 (input to fc1 MFMA) ----------------
__global__ void k_pool(const float* __restrict__ x, const int* __restrict__ gstart,
                       _Float16* __restrict__ hg16) {
    int g = blockIdx.y;
    int col = blockIdx.x * 256 + threadIdx.x;
    int r0 = gstart[g], r1 = gstart[g + 1];
    float s = 0.f;
    for (int r = r0; r < r1; ++r) s += x[(size_t)r * F + col];
    float inv = (r1 > r0) ? 1.f / (float)(r1 - r0) : 0.f;
    hg16[(size_t)g * F + col] = (_Float16)(s * inv);
}

// ---------------- MLP fc1/fc2: f16 MFMA GEMM, M=64, N=K=1024 ----------------
__launch_bounds__(256)
__global__ void k_mlp_mfma(const _Float16* __restrict__ A16, const _Float16* __restrict__ Bt,
                           const float* __restrict__ bias, _Float16* __restrict__ out16,
                           float* __restrict__ out32, int mode) {
    const int l = threadIdx.x & 63, w = threadIdx.x >> 6;
    const int bx = blockIdx.x;
    const int fko = (l >> 4) * 8;

    const _Float16* pa = A16 + (size_t)(w * 16 + (l & 15)) * 1024 + fko;
    const _Float16* pb = Bt + (size_t)(bx * 64 + (l & 15)) * 1024 + fko;

    f32x4 acc[4];
    const f32x4 fzero = {0.f, 0.f, 0.f, 0.f};
#pragma unroll
    for (int ni = 0; ni < 4; ++ni) acc[ni] = fzero;

#pragma unroll 4
    for (int k0 = 0; k0 < 1024; k0 += 32) {
        half8v a = *(const half8v*)(pa + k0);
#pragma unroll
        for (int ni = 0; ni < 4; ++ni) {
            half8v b = *(const half8v*)(pb + (size_t)ni * 16 * 1024 + k0);
            acc[ni] = __builtin_amdgcn_mfma_f32_16x16x32_f16(a, b, acc[ni], 0, 0, 0);
        }
    }

    const int row0 = w * 16 + (l >> 4) * 4;
    const int col0 = bx * 64 + (l & 15);
#pragma unroll
    for (int ni = 0; ni < 4; ++ni) {
        int col = col0 + ni * 16;
        float bb = bias[col];
#pragma unroll
        for (int r = 0; r < 4; ++r) {
            float v = acc[ni][r] + bb;
            v = v > 0.f ? v : 0.01f * v;
            if (mode == 0) out16[(size_t)(row0 + r) * 1024 + col] = (_Float16)v;
            else out32[(size_t)(row0 + r) * 1024 + col] = v;
        }
    }
}

// ---------------- fc3: one wave per output, f32 shfl reduction ----------------
__global__ void k_fc3(const float* __restrict__ z2, const float* __restrict__ W,
                      const float* __restrict__ b, float* __restrict__ out) {
    int gw = (blockIdx.x * blockDim.x + threadIdx.x) >> 6;
    int lane = threadIdx.x & 63;
    if (gw >= N_GRAPHS * NCLS) return;
    int row = gw / NCLS, col = gw - row * NCLS;
    float s = 0.f;
    for (int k = lane; k < 1024; k += 64) s += z2[(size_t)row * 1024 + k] * W[(size_t)k * NCLS + col];
#pragma unroll
    for (int o = 32; o; o >>= 1) s += __shfl_down(s, o);
    if (lane == 0) out[(size_t)row * NCLS + col] = s + b[col];
}

// ---------------- host orchestration ----------------
extern "C" void kernel_launch(void* const* d_in, const int* in_sizes, int n_in,
                              void* d_out, int out_size, void* d_ws, size_t ws_size,
                              hipStream_t stream) {
    const float* h = (const float*)d_in[0];
    const int* src = (const int*)d_in[1];
    const int* dst = (const int*)d_in[2];
    const int* gid = (const int*)d_in[3];

    const float *w_src[3], *b_src[3], *w_dst[3], *b_dst[3], *attn[3], *bias[3], *gamma[3], *beta[3];
    for (int l = 0; l < 3; ++l) {
        int base = 4 + l * 8;
        w_src[l] = (const float*)d_in[base + 0];
        b_src[l] = (const float*)d_in[base + 1];
        w_dst[l] = (const float*)d_in[base + 2];
        b_dst[l] = (const float*)d_in[base + 3];
        attn[l]  = (const float*)d_in[base + 4];
        bias[l]  = (const float*)d_in[base + 5];
        gamma[l] = (const float*)d_in[base + 6];
        beta[l]  = (const float*)d_in[base + 7];
    }
    const float* fc1_w = (const float*)d_in[28];
    const float* fc1_b = (const float*)d_in[29];
    const float* fc2_w = (const float*)d_in[30];
    const float* fc2_b = (const float*)d_in[31];
    const float* fc3_w = (const float*)d_in[32];
    const float* fc3_b = (const float*)d_in[33];

    // workspace carve
    char* base = (char*)d_ws;
    size_t o = 0;
    auto carve = [&](size_t bytes) -> char* {
        char* p = base + o;
        o += (bytes + 255) & ~(size_t)255;
        return p;
    };
    _Float16* fs16 = (_Float16*)carve((size_t)N_NODES * F * 2);
    _Float16* fd16 = (_Float16*)carve((size_t)N_NODES * F * 2);
    _Float16* y16 = (_Float16*)carve((size_t)N_NODES * F * 2);
    float* x32 = (float*)carve((size_t)N_NODES * F * 4);   // layer-3 BN output for pool
    _Float16* xh = (_Float16*)carve((size_t)N_PAD * F * 2);
    _Float16* wsh = (_Float16*)carve((size_t)F * F * 2);
    _Float16* wdh = (_Float16*)carve((size_t)F * F * 2);
    _Float16* fc1h = (_Float16*)carve((size_t)F * F * 2);
    _Float16* fc2h = (_Float16*)carve((size_t)F * F * 2);
    int* cnt = (int*)carve((size_t)N_NODES * 4);
    int* off = (int*)carve((size_t)(N_NODES + 1) * 4);
    int* cursor = (int*)carve((size_t)N_NODES * 4);
    int* csr_e = (int*)carve((size_t)N_EDGES * 4);
    float* part = (float*)carve((size_t)BN_CHUNKS * 2 * F * 4);
    float* scale = (float*)carve(F * 4);
    float* shift = (float*)carve(F * 4);
    int* gstart = (int*)carve((N_GRAPHS + 1) * 4);
    _Float16* hg16 = (_Float16*)carve((size_t)N_GRAPHS * F * 2);
    _Float16* z1h = (_Float16*)carve((size_t)N_GRAPHS * F * 2);
    float* z2 = (float*)carve((size_t)N_GRAPHS * F * 4);
    (void)ws_size;

    // ---- CSR build (deterministic: buckets sorted by edge id) ----
    k_zero_i32<<<(N_NODES + 255) / 256, 256, 0, stream>>>(cnt, N_NODES);
    k_count<<<(N_EDGES + 255) / 256, 256, 0, stream>>>(dst, cnt);
    k_scan<<<1, 256, 0, stream>>>(cnt, off);
    k_copy_i32<<<(N_NODES + 255) / 256, 256, 0, stream>>>(cursor, off, N_NODES);
    k_fill<<<(N_EDGES + 255) / 256, 256, 0, stream>>>(dst, cursor, csr_e);
    k_sort_buckets<<<(N_NODES + 255) / 256, 256, 0, stream>>>(off, csr_e);
    k_gstart<<<1, 128, 0, stream>>>(gid, gstart);

    // ---- input conversion + pad-row zeroing + MLP weight conversion ----
    k_cvt_h<<<(N_PAD * 64 + 255) / 256, 256, 0, stream>>>(h, xh);
    k_zero_pad<<<((N_PAD - N_NODES) * F + 255) / 256, 256, 0, stream>>>(xh);
    k_cvt_w2<<<dim3(F / 32, F / 32, 2), 256, 0, stream>>>(fc1_w, fc1h, fc2_w, fc2h, F, F);

    // ---- 3 GATv2 + BN + lrelu layers ----
    const dim3 ggrid(8, N_PAD / 128);
    for (int l = 0; l < 3; ++l) {
        const int K = (l == 0) ? IN_F : F;
        const int Kp = (l == 0) ? 64 : F;
        k_cvt_w2<<<dim3(Kp / 32, F / 32, 2), 256, 0, stream>>>(w_src[l], wsh, w_dst[l], wdh, K, Kp);
        k_gemm_dual<<<ggrid, 256, 0, stream>>>(xh, wsh, wdh, b_src[l], b_dst[l], fs16, fd16, Kp);
        k_gat<<<N_NODES, 256, 0, stream>>>(fs16, fd16, off, csr_e, src, attn[l], bias[l], y16);
        k_bnpart<<<BN_CHUNKS, 256, 0, stream>>>(y16, part);
        k_bnfin<<<F / 256, 256, 0, stream>>>(part, gamma[l], beta[l], scale, shift);
        k_bnapply<<<(N_NODES * (F / 4) + 255) / 256, 256, 0, stream>>>(
            y16, scale, shift, x32, xh, (l == 2) ? 1 : 0);
    }

    // ---- pool + MLP head (MFMA fc1/fc2, wave-reduce fc3) ----
    k_pool<<<dim3(4, N_GRAPHS), 256, 0, stream>>>(x32, gstart, hg16);
    k_mlp_mfma<<<16, 256, 0, stream>>>(hg16, fc1h, fc1_b, z1h, nullptr, 0);
    k_mlp_mfma<<<16, 256, 0, stream>>>(z1h, fc2h, fc2_b, nullptr, z2, 1);
    k_fc3<<<(N_GRAPHS * NCLS * 64 + 255) / 256, 256, 0, stream>>>(z2, fc3_w, fc3_b, (float*)d_out);
}

// Round 8
// 863.849 us; speedup vs baseline: 1.0189x; 1.0189x over previous
//
#include <hip/hip_runtime.h>
#include <math.h>

#define N_NODES 20000
#define N_PAD   20096            // 157 * 128
#define N_EDGES 100000
#define N_GRAPHS 64
#define IN_F 63
#define NHEAD 8
#define F 1024                   // NHEAD * HID
#define NCLS 18
#define BN_EPS 1e-5f
#define BN_CHUNKS 256

typedef __attribute__((ext_vector_type(8))) _Float16 half8v;  // 8 f16 (4 VGPRs)
typedef __attribute__((ext_vector_type(4))) _Float16 half4v;
typedef __attribute__((ext_vector_type(4))) float f32x4;

// ---------------- utility kernels ----------------
__global__ void k_zero_i32(int* __restrict__ p, int n) {
    int i = blockIdx.x * blockDim.x + threadIdx.x;
    if (i < n) p[i] = 0;
}

__global__ void k_copy_i32(int* __restrict__ d, const int* __restrict__ s, int n) {
    int i = blockIdx.x * blockDim.x + threadIdx.x;
    if (i < n) d[i] = s[i];
}

// ---------------- CSR build over dst ----------------
__global__ void k_count(const int* __restrict__ dst, int* __restrict__ cnt) {
    int i = blockIdx.x * blockDim.x + threadIdx.x;
    if (i < N_EDGES) atomicAdd(&cnt[dst[i]], 1);
}

__global__ void k_scan(const int* __restrict__ cnt, int* __restrict__ off) {
    __shared__ int tsum[256];
    const int CH = (N_NODES + 255) / 256;
    int t = threadIdx.x;
    int s = 0;
    for (int i = 0; i < CH; ++i) {
        int idx = t * CH + i;
        if (idx < N_NODES) s += cnt[idx];
    }
    tsum[t] = s;
    __syncthreads();
    if (t == 0) {
        int acc = 0;
        for (int i = 0; i < 256; ++i) { int v = tsum[i]; tsum[i] = acc; acc += v; }
    }
    __syncthreads();
    int run = tsum[t];
    for (int i = 0; i < CH; ++i) {
        int idx = t * CH + i;
        if (idx < N_NODES) { off[idx] = run; run += cnt[idx]; }
    }
    if (t == 255) off[N_NODES] = run;
}

__global__ void k_fill(const int* __restrict__ dst, int* __restrict__ cursor,
                       int* __restrict__ csr_e) {
    int i = blockIdx.x * blockDim.x + threadIdx.x;
    if (i < N_EDGES) {
        int p = atomicAdd(&cursor[dst[i]], 1);
        csr_e[p] = i;
    }
}

__global__ void k_sort_buckets(const int* __restrict__ off, int* __restrict__ csr_e) {
    int n = blockIdx.x * blockDim.x + threadIdx.x;
    if (n >= N_NODES) return;
    int b = off[n], e = off[n + 1];
    for (int i = b + 1; i < e; ++i) {
        int v = csr_e[i];
        int j = i - 1;
        while (j >= b && csr_e[j] > v) { csr_e[j + 1] = csr_e[j]; --j; }
        csr_e[j + 1] = v;
    }
}

__global__ void k_gstart(const int* __restrict__ gid, int* __restrict__ gstart) {
    int g = blockIdx.x * blockDim.x + threadIdx.x;
    if (g > N_GRAPHS) return;
    int lo = 0, hi = N_NODES;
    while (lo < hi) {
        int mid = (lo + hi) >> 1;
        if (gid[mid] < g) lo = mid + 1; else hi = mid;
    }
    gstart[g] = lo;
}

// ---------------- conversions for f16 GEMM ----------------
__global__ void k_cvt_h(const float* __restrict__ h, _Float16* __restrict__ xh) {
    int idx = blockIdx.x * 256 + threadIdx.x;
    if (idx >= N_PAD * 64) return;
    int m = idx >> 6, k = idx & 63;
    float v = (m < N_NODES && k < IN_F) ? h[m * IN_F + k] : 0.f;
    xh[idx] = (_Float16)v;
}

__global__ void k_zero_pad(_Float16* __restrict__ xh) {
    int idx = blockIdx.x * 256 + threadIdx.x;
    const int total = (N_PAD - N_NODES) * F;
    if (idx < total) xh[(size_t)N_NODES * F + idx] = (_Float16)0.f;
}

// W [K][1024] f32 -> W^T [1024][Kpad] f16; two matrices per launch (grid.z)
__global__ void k_cvt_w2(const float* __restrict__ W0, _Float16* __restrict__ o0,
                         const float* __restrict__ W1, _Float16* __restrict__ o1,
                         int K, int Kpad) {
    const float* W = blockIdx.z ? W1 : W0;
    _Float16* wh = blockIdx.z ? o1 : o0;
    __shared__ float t[32][33];
    int kt = blockIdx.x * 32, nt = blockIdx.y * 32;
    int tx = threadIdx.x & 31, ty = threadIdx.x >> 5;
#pragma unroll
    for (int j = 0; j < 4; ++j) {
        int k = kt + ty + j * 8;
        t[ty + j * 8][tx] = (k < K) ? W[(size_t)k * F + nt + tx] : 0.f;
    }
    __syncthreads();
#pragma unroll
    for (int j = 0; j < 4; ++j) {
        int n = nt + ty + j * 8;
        wh[(size_t)n * Kpad + kt + tx] = (_Float16)t[tx][ty + j * 8];
    }
}

// ---------------- f16 MFMA GEMM over concatenated W = [Ws^T; Wd^T] (2048 rows) ----
// C[20096][2048 logical] split as Cs (cols 0-1023) / Cd (cols 1024-2047), f16 out.
// 128x128 tile, 4 waves, TRUE double-buffered LDS (A+B, 64 KiB), T3 2-phase:
// {stage next buf first, ds_read+MFMA current, ONE barrier}. XOR swizzle as r5/r6
// (verified 0 conflicts). __launch_bounds__(256,4) caps regs at 128 -> 4 waves/SIMD.
#define AS1C(p) ((const __attribute__((address_space(1))) void*)(p))
#define AS3(p)  ((__attribute__((address_space(3))) void*)(p))

template <int KPAD>
__launch_bounds__(256, 4)
__global__ void k_gemm(const _Float16* __restrict__ A, const _Float16* __restrict__ W,
                       const float* __restrict__ bias_s, const float* __restrict__ bias_d,
                       _Float16* __restrict__ Cs, _Float16* __restrict__ Cd) {
    __shared__ _Float16 lds[2][2][128 * 64];   // [buf][A/B][128][64] f16 = 64 KiB
    const int l = threadIdx.x & 63, w = threadIdx.x >> 6;

    // XCD-aware bijective swizzle: nwg = 16*157 = 2512, 2512 % 8 == 0
    const int orig = blockIdx.y * 16 + blockIdx.x;
    const int wg = (orig & 7) * (2512 / 8) + (orig >> 3);
    const int by = wg >> 4, bx = wg & 15;

    // --- staging: wave w stages rows [w*32, w*32+32) of A and B tiles ---
    const int grow = w * 32 + (l >> 3);
    const int gcol = ((l & 7) ^ (l >> 3)) << 3;         // swizzled 16B chunk (halves)
    const size_t rstep = (size_t)8 * KPAD;
    const _Float16* gA = A + (size_t)(by * 128 + grow) * KPAD + gcol;
    const _Float16* gB = W + (size_t)(bx * 128 + grow) * KPAD + gcol;

    // --- fragment coords: wave (wr,wc) owns a 64x64 sub-tile ---
    const int wr = (w >> 1) * 64, wc = (w & 1) * 64;
    const int frow = l & 15;
    const int swz = (l & 7) << 4;                       // read-side XOR (row&7 == l&7)
    const int kbase = (l >> 4) * 16;                    // byte offset of k-chunk

    f32x4 acc[4][4];
    const f32x4 fzero = {0.f, 0.f, 0.f, 0.f};
#pragma unroll
    for (int i = 0; i < 4; ++i)
#pragma unroll
        for (int j = 0; j < 4; ++j) acc[i][j] = fzero;

    auto stage = [&](int b, int k0) {
        char* dA = (char*)&lds[b][0][0] + w * 4096;
        char* dB = (char*)&lds[b][1][0] + w * 4096;
#pragma unroll
        for (int j = 0; j < 4; ++j) {
            __builtin_amdgcn_global_load_lds(AS1C(gA + k0 + j * rstep), AS3(dA + j * 1024), 16, 0, 0);
            __builtin_amdgcn_global_load_lds(AS1C(gB + k0 + j * rstep), AS3(dB + j * 1024), 16, 0, 0);
        }
    };

    stage(0, 0);
    __syncthreads();

    int buf = 0;
#pragma unroll 1
    for (int k0 = 0; k0 < KPAD; k0 += 64) {
        if (k0 + 64 < KPAD) stage(buf ^ 1, k0 + 64);    // issue BEFORE compute (T3)

        const char* lA = (const char*)&lds[buf][0][0];
        const char* lB = (const char*)&lds[buf][1][0];
#pragma unroll
        for (int kk = 0; kk < 2; ++kk) {
            const int kb = (kk * 64 + kbase) ^ swz;
            half8v a[4];
#pragma unroll
            for (int mi = 0; mi < 4; ++mi) {
                int row = wr + mi * 16 + frow;
                a[mi] = *(const half8v*)(lA + row * 128 + kb);
            }
#pragma unroll
            for (int ni = 0; ni < 4; ++ni) {
                int rowb = wc + ni * 16 + frow;
                half8v b = *(const half8v*)(lB + rowb * 128 + kb);
#pragma unroll
                for (int mi = 0; mi < 4; ++mi)
                    acc[mi][ni] = __builtin_amdgcn_mfma_f32_16x16x32_f16(a[mi], b, acc[mi][ni], 0, 0, 0);
            }
        }
        __syncthreads();   // stage issued ~64 MFMAs ago -> drain finds it landed
        buf ^= 1;
    }

    // epilogue: C/D layout col = lane&15, row = (lane>>4)*4 + reg; f16 stores
    const bool isS = bx < 8;
    _Float16* __restrict__ C = isS ? Cs : Cd;
    const float* __restrict__ bias = isS ? bias_s : bias_d;
    const int crow0 = by * 128 + wr + (l >> 4) * 4;
    const int ccol = (bx & 7) * 128 + wc + (l & 15);
    float bb[4];
#pragma unroll
    for (int ni = 0; ni < 4; ++ni) bb[ni] = bias[ccol + ni * 16];
#pragma unroll
    for (int mi = 0; mi < 4; ++mi) {
#pragma unroll
        for (int r = 0; r < 4; ++r) {
            int row = crow0 + mi * 16 + r;
            if (row < N_NODES) {
#pragma unroll
                for (int ni = 0; ni < 4; ++ni)
                    C[(size_t)row * F + ccol + ni * 16] = (_Float16)(acc[mi][ni][r] + bb[ni]);
            }
        }
    }
}

// ---------------- fused GATv2 edge+softmax+aggregate (online softmax, f16 io) ----------------
__launch_bounds__(256)
__global__ void k_gat(const _Float16* __restrict__ fs, const _Float16* __restrict__ fd,
                      const int* __restrict__ off, const int* __restrict__ csr_e,
                      const int* __restrict__ src, const float* __restrict__ attn,
                      const float* __restrict__ bias, _Float16* __restrict__ y16) {
    __shared__ int s_src[256];
    const int n = blockIdx.x;
    const int t = threadIdx.x;
    const int b = off[n], e = off[n + 1];

    half4v fdv = *(const half4v*)(fd + (size_t)n * F + t * 4);
    const float fd0 = (float)fdv.x, fd1 = (float)fdv.y, fd2 = (float)fdv.z, fd3 = (float)fdv.w;
    const float4 av = *(const float4*)(attn + (t >> 5) * 128 + (t & 31) * 4);

    float m = -1e30f, den = 0.f;
    float ax = 0.f, ay = 0.f, az = 0.f, aw = 0.f;

    for (int c0 = b; c0 < e; c0 += 256) {
        int ncur = e - c0; if (ncur > 256) ncur = 256;
        __syncthreads();
        if (t < ncur) s_src[t] = src[csr_e[c0 + t]];
        __syncthreads();
        for (int i = 0; i < ncur; ++i) {
            int s = s_src[i];
            half4v fsv = *(const half4v*)(fs + (size_t)s * F + t * 4);
            float f0 = (float)fsv.x, f1 = (float)fsv.y, f2 = (float)fsv.z, f3 = (float)fsv.w;
            float vx = f0 + fd0; vx = vx > 0.f ? vx : 0.2f * vx;
            float vy = f1 + fd1; vy = vy > 0.f ? vy : 0.2f * vy;
            float vz = f2 + fd2; vz = vz > 0.f ? vz : 0.2f * vz;
            float vw = f3 + fd3; vw = vw > 0.f ? vw : 0.2f * vw;
            float p = vx * av.x + vy * av.y + vz * av.z + vw * av.w;
            p += __shfl_xor(p, 1);
            p += __shfl_xor(p, 2);
            p += __shfl_xor(p, 4);
            p += __shfl_xor(p, 8);
            p += __shfl_xor(p, 16);
            float mn = fmaxf(m, p);
            float so = __expf(m - mn);
            float wexp = __expf(p - mn);
            den = den * so + wexp;
            ax = ax * so + wexp * f0;
            ay = ay * so + wexp * f1;
            az = az * so + wexp * f2;
            aw = aw * so + wexp * f3;
            m = mn;
        }
    }
    float inv = (e > b) ? 1.f / den : 0.f;
    const float4 bb = *(const float4*)(bias + t * 4);
    half4v o;
    o.x = (_Float16)(ax * inv + bb.x);
    o.y = (_Float16)(ay * inv + bb.y);
    o.z = (_Float16)(az * inv + bb.z);
    o.w = (_Float16)(aw * inv + bb.w);
    *(half4v*)(y16 + (size_t)n * F + t * 4) = o;
}

// ---------------- BatchNorm (2-stage deterministic) + lrelu, f16 y ----------------
__global__ void k_bnpart(const _Float16* __restrict__ y16, float* __restrict__ part) {
    const int ROWS = (N_NODES + BN_CHUNKS - 1) / BN_CHUNKS;
    int blk = blockIdx.x;
    int t = threadIdx.x;
    int r0 = blk * ROWS;
    int r1 = r0 + ROWS; if (r1 > N_NODES) r1 = N_NODES;
    float sx = 0.f, sy = 0.f, sz = 0.f, sw = 0.f;
    float qx = 0.f, qy = 0.f, qz = 0.f, qw = 0.f;
    for (int r = r0; r < r1; ++r) {
        half4v v = *(const half4v*)(y16 + (size_t)r * F + t * 4);
        float vx = (float)v.x, vy = (float)v.y, vz = (float)v.z, vw = (float)v.w;
        sx += vx; sy += vy; sz += vz; sw += vw;
        qx += vx * vx; qy += vy * vy; qz += vz * vz; qw += vw * vw;
    }
    float4 s4; s4.x = sx; s4.y = sy; s4.z = sz; s4.w = sw;
    float4 q4; q4.x = qx; q4.y = qy; q4.z = qz; q4.w = qw;
    *(float4*)(part + (size_t)blk * (2 * F) + t * 4) = s4;
    *(float4*)(part + (size_t)blk * (2 * F) + F + t * 4) = q4;
}

__global__ void k_bnfin(const float* __restrict__ part, const float* __restrict__ gamma,
                        const float* __restrict__ beta, float* __restrict__ scale,
                        float* __restrict__ shift) {
    int c = blockIdx.x * blockDim.x + threadIdx.x;
    if (c >= F) return;
    float s = 0.f, q = 0.f;
    for (int b = 0; b < BN_CHUNKS; ++b) {
        s += part[(size_t)b * (2 * F) + c];
        q += part[(size_t)b * (2 * F) + F + c];
    }
    float mu = s / (float)N_NODES;
    float var = q / (float)N_NODES - mu * mu;
    float sc = gamma[c] * rsqrtf(var + BN_EPS);
    scale[c] = sc;
    shift[c] = beta[c] - mu * sc;
}

// BN+lrelu from f16 y; mode 0: emit f16 xh (layers 1,2); mode 1: emit f32 x (layer 3)
__global__ void k_bnapply(const _Float16* __restrict__ y16, const float* __restrict__ scale,
                          const float* __restrict__ shift, float* __restrict__ x,
                          _Float16* __restrict__ xh, int mode) {
    int i = blockIdx.x * blockDim.x + threadIdx.x;
    if (i >= N_NODES * (F / 4)) return;
    int c4 = (i & (F / 4 - 1)) * 4;
    half4v v = ((const half4v*)y16)[i];
    float4 o;
    o.x = (float)v.x * scale[c4 + 0] + shift[c4 + 0];
    o.y = (float)v.y * scale[c4 + 1] + shift[c4 + 1];
    o.z = (float)v.z * scale[c4 + 2] + shift[c4 + 2];
    o.w = (float)v.w * scale[c4 + 3] + shift[c4 + 3];
    o.x = o.x > 0.f ? o.x : 0.01f * o.x;
    o.y = o.y > 0.f ? o.y : 0.01f * o.y;
    o.z = o.z > 0.f ? o.z : 0.01f * o.z;
    o.w = o.w > 0.f ? o.w : 0.01f * o.w;
    if (mode == 0) {
        half4v h4;
        h4.x = (_Float16)o.x; h4.y = (_Float16)o.y;
        h4.z = (_Float16)o.z; h4.w = (_Float16)o.w;
        *(half4v*)&xh[(size_t)i * 4] = h4;
    } else {
        ((float4*)x)[i] = o;
    }
}

// ---------------- avg pool per graph -> f16 (input to fc1 MFMA) ----------------
__global__ void k_pool(const float* __restrict__ x, const int* __restrict__ gstart,
                       _Float16* __restrict__ hg16) {
    int g = blockIdx.y;
    int col = blockIdx.x * 256 + threadIdx.x;
    int r0 = gstart[g], r1 = gstart[g + 1];
    float s = 0.f;
    for (int r = r0; r < r1; ++r) s += x[(size_t)r * F + col];
    float inv = (r1 > r0) ? 1.f / (float)(r1 - r0) : 0.f;
    hg16[(size_t)g * F + col] = (_Float16)(s * inv);
}

// ---------------- MLP fc1/fc2: f16 MFMA GEMM, M=64, N=K=1024 ----------------
__launch_bounds__(256)
__global__ void k_mlp_mfma(const _Float16* __restrict__ A16, const _Float16* __restrict__ Bt,
                           const float* __restrict__ bias, _Float16* __restrict__ out16,
                           float* __restrict__ out32, int mode) {
    const int l = threadIdx.x & 63, w = threadIdx.x >> 6;
    const int bx = blockIdx.x;
    const int fko = (l >> 4) * 8;

    const _Float16* pa = A16 + (size_t)(w * 16 + (l & 15)) * 1024 + fko;
    const _Float16* pb = Bt + (size_t)(bx * 64 + (l & 15)) * 1024 + fko;

    f32x4 acc[4];
    const f32x4 fzero = {0.f, 0.f, 0.f, 0.f};
#pragma unroll
    for (int ni = 0; ni < 4; ++ni) acc[ni] = fzero;

#pragma unroll 4
    for (int k0 = 0; k0 < 1024; k0 += 32) {
        half8v a = *(const half8v*)(pa + k0);
#pragma unroll
        for (int ni = 0; ni < 4; ++ni) {
            half8v b = *(const half8v*)(pb + (size_t)ni * 16 * 1024 + k0);
            acc[ni] = __builtin_amdgcn_mfma_f32_16x16x32_f16(a, b, acc[ni], 0, 0, 0);
        }
    }

    const int row0 = w * 16 + (l >> 4) * 4;
    const int col0 = bx * 64 + (l & 15);
#pragma unroll
    for (int ni = 0; ni < 4; ++ni) {
        int col = col0 + ni * 16;
        float bb = bias[col];
#pragma unroll
        for (int r = 0; r < 4; ++r) {
            float v = acc[ni][r] + bb;
            v = v > 0.f ? v : 0.01f * v;
            if (mode == 0) out16[(size_t)(row0 + r) * 1024 + col] = (_Float16)v;
            else out32[(size_t)(row0 + r) * 1024 + col] = v;
        }
    }
}

// ---------------- fc3: one wave per output, f32 shfl reduction ----------------
__global__ void k_fc3(const float* __restrict__ z2, const float* __restrict__ W,
                      const float* __restrict__ b, float* __restrict__ out) {
    int gw = (blockIdx.x * blockDim.x + threadIdx.x) >> 6;
    int lane = threadIdx.x & 63;
    if (gw >= N_GRAPHS * NCLS) return;
    int row = gw / NCLS, col = gw - row * NCLS;
    float s = 0.f;
    for (int k = lane; k < 1024; k += 64) s += z2[(size_t)row * 1024 + k] * W[(size_t)k * NCLS + col];
#pragma unroll
    for (int o = 32; o; o >>= 1) s += __shfl_down(s, o);
    if (lane == 0) out[(size_t)row * NCLS + col] = s + b[col];
}

// ---------------- host orchestration ----------------
extern "C" void kernel_launch(void* const* d_in, const int* in_sizes, int n_in,
                              void* d_out, int out_size, void* d_ws, size_t ws_size,
                              hipStream_t stream) {
    const float* h = (const float*)d_in[0];
    const int* src = (const int*)d_in[1];
    const int* dst = (const int*)d_in[2];
    const int* gid = (const int*)d_in[3];

    const float *w_src[3], *b_src[3], *w_dst[3], *b_dst[3], *attn[3], *bias[3], *gamma[3], *beta[3];
    for (int l = 0; l < 3; ++l) {
        int base = 4 + l * 8;
        w_src[l] = (const float*)d_in[base + 0];
        b_src[l] = (const float*)d_in[base + 1];
        w_dst[l] = (const float*)d_in[base + 2];
        b_dst[l] = (const float*)d_in[base + 3];
        attn[l]  = (const float*)d_in[base + 4];
        bias[l]  = (const float*)d_in[base + 5];
        gamma[l] = (const float*)d_in[base + 6];
        beta[l]  = (const float*)d_in[base + 7];
    }
    const float* fc1_w = (const float*)d_in[28];
    const float* fc1_b = (const float*)d_in[29];
    const float* fc2_w = (const float*)d_in[30];
    const float* fc2_b = (const float*)d_in[31];
    const float* fc3_w = (const float*)d_in[32];
    const float* fc3_b = (const float*)d_in[33];

    // workspace carve
    char* base = (char*)d_ws;
    size_t o = 0;
    auto carve = [&](size_t bytes) -> char* {
        char* p = base + o;
        o += (bytes + 255) & ~(size_t)255;
        return p;
    };
    _Float16* fs16 = (_Float16*)carve((size_t)N_NODES * F * 2);
    _Float16* fd16 = (_Float16*)carve((size_t)N_NODES * F * 2);
    _Float16* y16 = (_Float16*)carve((size_t)N_NODES * F * 2);
    float* x32 = (float*)carve((size_t)N_NODES * F * 4);   // layer-3 BN output for pool
    _Float16* xh = (_Float16*)carve((size_t)N_PAD * F * 2);
    _Float16* wcat = (_Float16*)carve((size_t)2 * F * F * 2);  // [Ws^T ; Wd^T]
    _Float16* fc1h = (_Float16*)carve((size_t)F * F * 2);
    _Float16* fc2h = (_Float16*)carve((size_t)F * F * 2);
    int* cnt = (int*)carve((size_t)N_NODES * 4);
    int* off = (int*)carve((size_t)(N_NODES + 1) * 4);
    int* cursor = (int*)carve((size_t)N_NODES * 4);
    int* csr_e = (int*)carve((size_t)N_EDGES * 4);
    float* part = (float*)carve((size_t)BN_CHUNKS * 2 * F * 4);
    float* scale = (float*)carve(F * 4);
    float* shift = (float*)carve(F * 4);
    int* gstart = (int*)carve((N_GRAPHS + 1) * 4);
    _Float16* hg16 = (_Float16*)carve((size_t)N_GRAPHS * F * 2);
    _Float16* z1h = (_Float16*)carve((size_t)N_GRAPHS * F * 2);
    float* z2 = (float*)carve((size_t)N_GRAPHS * F * 4);
    (void)ws_size;

    // ---- CSR build (deterministic: buckets sorted by edge id) ----
    k_zero_i32<<<(N_NODES + 255) / 256, 256, 0, stream>>>(cnt, N_NODES);
    k_count<<<(N_EDGES + 255) / 256, 256, 0, stream>>>(dst, cnt);
    k_scan<<<1, 256, 0, stream>>>(cnt, off);
    k_copy_i32<<<(N_NODES + 255) / 256, 256, 0, stream>>>(cursor, off, N_NODES);
    k_fill<<<(N_EDGES + 255) / 256, 256, 0, stream>>>(dst, cursor, csr_e);
    k_sort_buckets<<<(N_NODES + 255) / 256, 256, 0, stream>>>(off, csr_e);
    k_gstart<<<1, 128, 0, stream>>>(gid, gstart);

    // ---- input conversion + pad-row zeroing + MLP weight conversion ----
    k_cvt_h<<<(N_PAD * 64 + 255) / 256, 256, 0, stream>>>(h, xh);
    k_zero_pad<<<((N_PAD - N_NODES) * F + 255) / 256, 256, 0, stream>>>(xh);
    k_cvt_w2<<<dim3(F / 32, F / 32, 2), 256, 0, stream>>>(fc1_w, fc1h, fc2_w, fc2h, F, F);

    // ---- 3 GATv2 + BN + lrelu layers ----
    const dim3 ggrid(16, N_PAD / 128);
    for (int l = 0; l < 3; ++l) {
        const int K = (l == 0) ? IN_F : F;
        const int Kp = (l == 0) ? 64 : F;
        k_cvt_w2<<<dim3(Kp / 32, F / 32, 2), 256, 0, stream>>>(
            w_src[l], wcat, w_dst[l], wcat + (size_t)F * Kp, K, Kp);
        if (Kp == 64)
            k_gemm<64><<<ggrid, 256, 0, stream>>>(xh, wcat, b_src[l], b_dst[l], fs16, fd16);
        else
            k_gemm<1024><<<ggrid, 256, 0, stream>>>(xh, wcat, b_src[l], b_dst[l], fs16, fd16);
        k_gat<<<N_NODES, 256, 0, stream>>>(fs16, fd16, off, csr_e, src, attn[l], bias[l], y16);
        k_bnpart<<<BN_CHUNKS, 256, 0, stream>>>(y16, part);
        k_bnfin<<<F / 256, 256, 0, stream>>>(part, gamma[l], beta[l], scale, shift);
        k_bnapply<<<(N_NODES * (F / 4) + 255) / 256, 256, 0, stream>>>(
            y16, scale, shift, x32, xh, (l == 2) ? 1 : 0);
    }

    // ---- pool + MLP head (MFMA fc1/fc2, wave-reduce fc3) ----
    k_pool<<<dim3(4, N_GRAPHS), 256, 0, stream>>>(x32, gstart, hg16);
    k_mlp_mfma<<<16, 256, 0, stream>>>(hg16, fc1h, fc1_b, z1h, nullptr, 0);
    k_mlp_mfma<<<16, 256, 0, stream>>>(z1h, fc2h, fc2_b, nullptr, z2, 1);
    k_fc3<<<(N_GRAPHS * NCLS * 64 + 255) / 256, 256, 0, stream>>>(z2, fc3_w, fc3_b, (float*)d_out);
}

// Round 9
// 793.200 us; speedup vs baseline: 1.1096x; 1.0891x over previous
//
#include <hip/hip_runtime.h>
#include <math.h>

#define N_NODES 20000
#define N_PAD   20096            // 157 * 128
#define N_EDGES 100000
#define N_GRAPHS 64
#define IN_F 63
#define NHEAD 8
#define F 1024                   // NHEAD * HID
#define NCLS 18
#define BN_EPS 1e-5f
#define BN_CHUNKS 256

typedef __attribute__((ext_vector_type(8))) _Float16 half8v;  // 8 f16 (4 VGPRs)
typedef __attribute__((ext_vector_type(4))) _Float16 half4v;
typedef __attribute__((ext_vector_type(4))) float f32x4;

// ---------------- utility kernels ----------------
__global__ void k_zero_i32(int* __restrict__ p, int n) {
    int i = blockIdx.x * blockDim.x + threadIdx.x;
    if (i < n) p[i] = 0;
}

__global__ void k_copy_i32(int* __restrict__ d, const int* __restrict__ s, int n) {
    int i = blockIdx.x * blockDim.x + threadIdx.x;
    if (i < n) d[i] = s[i];
}

// ---------------- CSR build over dst ----------------
__global__ void k_count(const int* __restrict__ dst, int* __restrict__ cnt) {
    int i = blockIdx.x * blockDim.x + threadIdx.x;
    if (i < N_EDGES) atomicAdd(&cnt[dst[i]], 1);
}

__global__ void k_scan(const int* __restrict__ cnt, int* __restrict__ off) {
    __shared__ int tsum[256];
    const int CH = (N_NODES + 255) / 256;
    int t = threadIdx.x;
    int s = 0;
    for (int i = 0; i < CH; ++i) {
        int idx = t * CH + i;
        if (idx < N_NODES) s += cnt[idx];
    }
    tsum[t] = s;
    __syncthreads();
    if (t == 0) {
        int acc = 0;
        for (int i = 0; i < 256; ++i) { int v = tsum[i]; tsum[i] = acc; acc += v; }
    }
    __syncthreads();
    int run = tsum[t];
    for (int i = 0; i < CH; ++i) {
        int idx = t * CH + i;
        if (idx < N_NODES) { off[idx] = run; run += cnt[idx]; }
    }
    if (t == 255) off[N_NODES] = run;
}

__global__ void k_fill(const int* __restrict__ dst, int* __restrict__ cursor,
                       int* __restrict__ csr_e) {
    int i = blockIdx.x * blockDim.x + threadIdx.x;
    if (i < N_EDGES) {
        int p = atomicAdd(&cursor[dst[i]], 1);
        csr_e[p] = i;
    }
}

__global__ void k_sort_buckets(const int* __restrict__ off, int* __restrict__ csr_e) {
    int n = blockIdx.x * blockDim.x + threadIdx.x;
    if (n >= N_NODES) return;
    int b = off[n], e = off[n + 1];
    for (int i = b + 1; i < e; ++i) {
        int v = csr_e[i];
        int j = i - 1;
        while (j >= b && csr_e[j] > v) { csr_e[j + 1] = csr_e[j]; --j; }
        csr_e[j + 1] = v;
    }
}

__global__ void k_gstart(const int* __restrict__ gid, int* __restrict__ gstart) {
    int g = blockIdx.x * blockDim.x + threadIdx.x;
    if (g > N_GRAPHS) return;
    int lo = 0, hi = N_NODES;
    while (lo < hi) {
        int mid = (lo + hi) >> 1;
        if (gid[mid] < g) lo = mid + 1; else hi = mid;
    }
    gstart[g] = lo;
}

// ---------------- conversions for f16 GEMM ----------------
__global__ void k_cvt_h(const float* __restrict__ h, _Float16* __restrict__ xh) {
    int idx = blockIdx.x * 256 + threadIdx.x;
    if (idx >= N_PAD * 64) return;
    int m = idx >> 6, k = idx & 63;
    float v = (m < N_NODES && k < IN_F) ? h[m * IN_F + k] : 0.f;
    xh[idx] = (_Float16)v;
}

__global__ void k_zero_pad(_Float16* __restrict__ xh) {
    int idx = blockIdx.x * 256 + threadIdx.x;
    const int total = (N_PAD - N_NODES) * F;
    if (idx < total) xh[(size_t)N_NODES * F + idx] = (_Float16)0.f;
}

// W [K][1024] f32 -> W^T [1024][Kpad] f16; two matrices per launch (grid.z)
__global__ void k_cvt_w2(const float* __restrict__ W0, _Float16* __restrict__ o0,
                         const float* __restrict__ W1, _Float16* __restrict__ o1,
                         int K, int Kpad) {
    const float* W = blockIdx.z ? W1 : W0;
    _Float16* wh = blockIdx.z ? o1 : o0;
    __shared__ float t[32][33];
    int kt = blockIdx.x * 32, nt = blockIdx.y * 32;
    int tx = threadIdx.x & 31, ty = threadIdx.x >> 5;
#pragma unroll
    for (int j = 0; j < 4; ++j) {
        int k = kt + ty + j * 8;
        t[ty + j * 8][tx] = (k < K) ? W[(size_t)k * F + nt + tx] : 0.f;
    }
    __syncthreads();
#pragma unroll
    for (int j = 0; j < 4; ++j) {
        int n = nt + ty + j * 8;
        wh[(size_t)n * Kpad + kt + tx] = (_Float16)t[tx][ty + j * 8];
    }
}

// ---------------- fused dual f16 MFMA GEMM: counted-vmcnt 3-buffer pipeline -----
// Dual (fs,fd share A fragments -> best MFMA:ds_read ratio). BK=32 tiles (64B rows),
// 3 tiles x 3 bufs = 72 KiB LDS, 2 blocks/CU. Loop per K-step:
//   {vmcnt(6); s_barrier; sched_barrier; stage(t+2); compute(t)}
// Raw barrier (no implicit vmcnt-0 drain); counted vmcnt waits only for the tile
// about to be computed; each stage has ~2 K-steps of MFMA to land (T3/T4 minimum).
// Hazards: stage(t+2) overwrites b[(t-1)%3] whose readers all passed this barrier;
// ds_reads fenced by asm "memory" clobber; all ds_reads lgkm-consumed pre-barrier.
// Swizzle s(r) = (r&3)^((r>>2)&3): LDS[r][c] = G[r][c^s(r)] (stage-side pre-swizzled
// global chunk), read chunk g at LDS[r][g^s(r)]. Bank audit: 16-lane fragment group
// maps 2 lanes per 16B slot = 2-way (free, m136).
#define AS1C(p) ((const __attribute__((address_space(1))) void*)(p))
#define AS3(p)  ((__attribute__((address_space(3))) void*)(p))

template <int KPAD>
__launch_bounds__(256, 2)
__global__ void k_gemm_dual(const _Float16* __restrict__ A,
                            const _Float16* __restrict__ Bs, const _Float16* __restrict__ Bd,
                            const float* __restrict__ bias_s, const float* __restrict__ bias_d,
                            _Float16* __restrict__ Cs, _Float16* __restrict__ Cd) {
    __shared__ _Float16 lds[3][3][128 * 32];   // [buf][A/Bs/Bd][128 rows][32 halves] = 72 KiB
    const int l = threadIdx.x & 63, w = threadIdx.x >> 6;

    // XCD-aware bijective swizzle: nwg = 8*157 = 1256, 1256 % 8 == 0
    const int orig = blockIdx.y * 8 + blockIdx.x;
    const int wg = (orig & 7) * (N_PAD / 128) + (orig >> 3);
    const int by = wg >> 3, bx = wg & 7;

    // --- staging lane map: call j covers rows [j*64, j*64+64); this wave rows w*16+(l>>2) ---
    const int srow = w * 16 + (l >> 2);
    const int schunk = ((l & 3) ^ ((l >> 2) & 3) ^ ((l >> 4) & 3)) << 3;   // halves
    const _Float16* gA  = A  + (size_t)(by * 128 + srow) * KPAD + schunk;
    const _Float16* gBs = Bs + (size_t)(bx * 128 + srow) * KPAD + schunk;
    const _Float16* gBd = Bd + (size_t)(bx * 128 + srow) * KPAD + schunk;
    const size_t jstep = (size_t)64 * KPAD;

    // --- fragment coords: wave (wr,wc) owns a 64x64 sub-tile of each output ---
    const int wr = (w >> 1) * 64, wc = (w & 1) * 64;
    const int frow = l & 15;
    // read byte offset within 64B row: chunk g=(l>>4) XOR s(r) with r&3=l&3,(r>>2)&3=(l>>2)&3
    const int kbyte = ((l & 3) ^ ((l >> 2) & 3) ^ ((l >> 4) & 3)) << 4;

    f32x4 accS[4][4], accD[4][4];
    const f32x4 fzero = {0.f, 0.f, 0.f, 0.f};
#pragma unroll
    for (int i = 0; i < 4; ++i)
#pragma unroll
        for (int j = 0; j < 4; ++j) { accS[i][j] = fzero; accD[i][j] = fzero; }

    auto stage = [&](int b, int t) {
        const int k0 = t * 32;
        char* dA  = (char*)&lds[b][0][0] + w * 1024;
        char* dBs = (char*)&lds[b][1][0] + w * 1024;
        char* dBd = (char*)&lds[b][2][0] + w * 1024;
#pragma unroll
        for (int j = 0; j < 2; ++j) {
            __builtin_amdgcn_global_load_lds(AS1C(gA  + k0 + j * jstep), AS3(dA  + j * 4096), 16, 0, 0);
            __builtin_amdgcn_global_load_lds(AS1C(gBs + k0 + j * jstep), AS3(dBs + j * 4096), 16, 0, 0);
            __builtin_amdgcn_global_load_lds(AS1C(gBd + k0 + j * jstep), AS3(dBd + j * 4096), 16, 0, 0);
        }
    };

    auto compute = [&](int b) {
        const char* lA  = (const char*)&lds[b][0][0];
        const char* lBs = (const char*)&lds[b][1][0];
        const char* lBd = (const char*)&lds[b][2][0];
        half8v a[4];
#pragma unroll
        for (int mi = 0; mi < 4; ++mi)
            a[mi] = *(const half8v*)(lA + (wr + mi * 16 + frow) * 64 + kbyte);
#pragma unroll
        for (int ni = 0; ni < 4; ++ni) {
            const int rb = (wc + ni * 16 + frow) * 64 + kbyte;
            half8v bs = *(const half8v*)(lBs + rb);
            half8v bd = *(const half8v*)(lBd + rb);
#pragma unroll
            for (int mi = 0; mi < 4; ++mi) {
                accS[mi][ni] = __builtin_amdgcn_mfma_f32_16x16x32_f16(a[mi], bs, accS[mi][ni], 0, 0, 0);
                accD[mi][ni] = __builtin_amdgcn_mfma_f32_16x16x32_f16(a[mi], bd, accD[mi][ni], 0, 0, 0);
            }
        }
    };

    constexpr int NT = KPAD / 32;
    stage(0, 0);
    if (NT > 1) stage(1, 1);
#pragma unroll 1
    for (int t = 0; t < NT; ++t) {
        if (t == NT - 1) asm volatile("s_waitcnt vmcnt(0)" ::: "memory");
        else             asm volatile("s_waitcnt vmcnt(6)" ::: "memory");
        __builtin_amdgcn_s_barrier();
        __builtin_amdgcn_sched_barrier(0);
        if (t + 2 < NT) stage((t + 2) % 3, t + 2);
        compute(t % 3);
    }

    // epilogue: C/D layout col = lane&15, row = (lane>>4)*4 + reg; f16 stores
    const int crow0 = by * 128 + wr + (l >> 4) * 4;
    const int ccol = bx * 128 + wc + (l & 15);
    float bS[4], bD[4];
#pragma unroll
    for (int ni = 0; ni < 4; ++ni) { bS[ni] = bias_s[ccol + ni * 16]; bD[ni] = bias_d[ccol + ni * 16]; }
#pragma unroll
    for (int mi = 0; mi < 4; ++mi) {
#pragma unroll
        for (int r = 0; r < 4; ++r) {
            int row = crow0 + mi * 16 + r;
            if (row < N_NODES) {
#pragma unroll
                for (int ni = 0; ni < 4; ++ni) {
                    int col = ccol + ni * 16;
                    Cs[(size_t)row * F + col] = (_Float16)(accS[mi][ni][r] + bS[ni]);
                    Cd[(size_t)row * F + col] = (_Float16)(accD[mi][ni][r] + bD[ni]);
                }
            }
        }
    }
}

// ---------------- fused GATv2 edge+softmax+aggregate (online softmax, f16 io) ----
// 128 threads/block, one block per dst node; 8 f16 per thread (16B/lane half8v).
// Head = 16 consecutive threads; score reduce via shfl_xor 1,2,4,8.
__launch_bounds__(128)
__global__ void k_gat(const _Float16* __restrict__ fs, const _Float16* __restrict__ fd,
                      const int* __restrict__ off, const int* __restrict__ csr_e,
                      const int* __restrict__ src, const float* __restrict__ attn,
                      const float* __restrict__ bias, _Float16* __restrict__ y16) {
    __shared__ int s_src[128];
    const int n = blockIdx.x;
    const int t = threadIdx.x;
    const int b = off[n], e = off[n + 1];

    half8v fdv8 = *(const half8v*)(fd + (size_t)n * F + t * 8);
    float fdv[8], av[8];
    const float4 a0 = *(const float4*)(attn + (t >> 4) * 128 + (t & 15) * 8);
    const float4 a1 = *(const float4*)(attn + (t >> 4) * 128 + (t & 15) * 8 + 4);
    av[0] = a0.x; av[1] = a0.y; av[2] = a0.z; av[3] = a0.w;
    av[4] = a1.x; av[5] = a1.y; av[6] = a1.z; av[7] = a1.w;
#pragma unroll
    for (int j = 0; j < 8; ++j) fdv[j] = (float)fdv8[j];

    float m = -1e30f, den = 0.f;
    float acc[8] = {0.f, 0.f, 0.f, 0.f, 0.f, 0.f, 0.f, 0.f};

    for (int c0 = b; c0 < e; c0 += 128) {
        int ncur = e - c0; if (ncur > 128) ncur = 128;
        __syncthreads();
        if (t < ncur) s_src[t] = src[csr_e[c0 + t]];
        __syncthreads();
        for (int i = 0; i < ncur; ++i) {
            int s = s_src[i];
            half8v fsv8 = *(const half8v*)(fs + (size_t)s * F + t * 8);
            float f[8];
            float p = 0.f;
#pragma unroll
            for (int j = 0; j < 8; ++j) {
                f[j] = (float)fsv8[j];
                float v = f[j] + fdv[j];
                v = v > 0.f ? v : 0.2f * v;
                p += v * av[j];
            }
            p += __shfl_xor(p, 1);
            p += __shfl_xor(p, 2);
            p += __shfl_xor(p, 4);
            p += __shfl_xor(p, 8);     // 16-lane head group holds full score
            float mn = fmaxf(m, p);
            float so = __expf(m - mn);
            float wexp = __expf(p - mn);
            den = den * so + wexp;
#pragma unroll
            for (int j = 0; j < 8; ++j) acc[j] = acc[j] * so + wexp * f[j];
            m = mn;
        }
    }
    float inv = (e > b) ? 1.f / den : 0.f;
    const float4 b0 = *(const float4*)(bias + t * 8);
    const float4 b1 = *(const float4*)(bias + t * 8 + 4);
    float bb[8] = {b0.x, b0.y, b0.z, b0.w, b1.x, b1.y, b1.z, b1.w};
    half8v o;
#pragma unroll
    for (int j = 0; j < 8; ++j) o[j] = (_Float16)(acc[j] * inv + bb[j]);
    *(half8v*)(y16 + (size_t)n * F + t * 8) = o;
}

// ---------------- BatchNorm (2-stage deterministic) + lrelu, f16 y ----------------
__global__ void k_bnpart(const _Float16* __restrict__ y16, float* __restrict__ part) {
    const int ROWS = (N_NODES + BN_CHUNKS - 1) / BN_CHUNKS;
    int blk = blockIdx.x;
    int t = threadIdx.x;
    int r0 = blk * ROWS;
    int r1 = r0 + ROWS; if (r1 > N_NODES) r1 = N_NODES;
    float sx = 0.f, sy = 0.f, sz = 0.f, sw = 0.f;
    float qx = 0.f, qy = 0.f, qz = 0.f, qw = 0.f;
    for (int r = r0; r < r1; ++r) {
        half4v v = *(const half4v*)(y16 + (size_t)r * F + t * 4);
        float vx = (float)v.x, vy = (float)v.y, vz = (float)v.z, vw = (float)v.w;
        sx += vx; sy += vy; sz += vz; sw += vw;
        qx += vx * vx; qy += vy * vy; qz += vz * vz; qw += vw * vw;
    }
    float4 s4; s4.x = sx; s4.y = sy; s4.z = sz; s4.w = sw;
    float4 q4; q4.x = qx; q4.y = qy; q4.z = qz; q4.w = qw;
    *(float4*)(part + (size_t)blk * (2 * F) + t * 4) = s4;
    *(float4*)(part + (size_t)blk * (2 * F) + F + t * 4) = q4;
}

__global__ void k_bnfin(const float* __restrict__ part, const float* __restrict__ gamma,
                        const float* __restrict__ beta, float* __restrict__ scale,
                        float* __restrict__ shift) {
    int c = blockIdx.x * blockDim.x + threadIdx.x;
    if (c >= F) return;
    float s = 0.f, q = 0.f;
    for (int b = 0; b < BN_CHUNKS; ++b) {
        s += part[(size_t)b * (2 * F) + c];
        q += part[(size_t)b * (2 * F) + F + c];
    }
    float mu = s / (float)N_NODES;
    float var = q / (float)N_NODES - mu * mu;
    float sc = gamma[c] * rsqrtf(var + BN_EPS);
    scale[c] = sc;
    shift[c] = beta[c] - mu * sc;
}

// BN+lrelu from f16 y; mode 0: emit f16 xh (layers 1,2); mode 1: emit f32 x (layer 3)
__global__ void k_bnapply(const _Float16* __restrict__ y16, const float* __restrict__ scale,
                          const float* __restrict__ shift, float* __restrict__ x,
                          _Float16* __restrict__ xh, int mode) {
    int i = blockIdx.x * blockDim.x + threadIdx.x;
    if (i >= N_NODES * (F / 4)) return;
    int c4 = (i & (F / 4 - 1)) * 4;
    half4v v = ((const half4v*)y16)[i];
    float4 o;
    o.x = (float)v.x * scale[c4 + 0] + shift[c4 + 0];
    o.y = (float)v.y * scale[c4 + 1] + shift[c4 + 1];
    o.z = (float)v.z * scale[c4 + 2] + shift[c4 + 2];
    o.w = (float)v.w * scale[c4 + 3] + shift[c4 + 3];
    o.x = o.x > 0.f ? o.x : 0.01f * o.x;
    o.y = o.y > 0.f ? o.y : 0.01f * o.y;
    o.z = o.z > 0.f ? o.z : 0.01f * o.z;
    o.w = o.w > 0.f ? o.w : 0.01f * o.w;
    if (mode == 0) {
        half4v h4;
        h4.x = (_Float16)o.x; h4.y = (_Float16)o.y;
        h4.z = (_Float16)o.z; h4.w = (_Float16)o.w;
        *(half4v*)&xh[(size_t)i * 4] = h4;
    } else {
        ((float4*)x)[i] = o;
    }
}

// ---------------- avg pool per graph -> f16 (input to fc1 MFMA) ----------------
__global__ void k_pool(const float* __restrict__ x, const int* __restrict__ gstart,
                       _Float16* __restrict__ hg16) {
    int g = blockIdx.y;
    int col = blockIdx.x * 256 + threadIdx.x;
    int r0 = gstart[g], r1 = gstart[g + 1];
    float s = 0.f;
    for (int r = r0; r < r1; ++r) s += x[(size_t)r * F + col];
    float inv = (r1 > r0) ? 1.f / (float)(r1 - r0) : 0.f;
    hg16[(size_t)g * F + col] = (_Float16)(s * inv);
}

// ---------------- MLP fc1/fc2: f16 MFMA GEMM, M=64, N=K=1024 ----------------
__launch_bounds__(256)
__global__ void k_mlp_mfma(const _Float16* __restrict__ A16, const _Float16* __restrict__ Bt,
                           const float* __restrict__ bias, _Float16* __restrict__ out16,
                           float* __restrict__ out32, int mode) {
    const int l = threadIdx.x & 63, w = threadIdx.x >> 6;
    const int bx = blockIdx.x;
    const int fko = (l >> 4) * 8;

    const _Float16* pa = A16 + (size_t)(w * 16 + (l & 15)) * 1024 + fko;
    const _Float16* pb = Bt + (size_t)(bx * 64 + (l & 15)) * 1024 + fko;

    f32x4 acc[4];
    const f32x4 fzero = {0.f, 0.f, 0.f, 0.f};
#pragma unroll
    for (int ni = 0; ni < 4; ++ni) acc[ni] = fzero;

#pragma unroll 4
    for (int k0 = 0; k0 < 1024; k0 += 32) {
        half8v a = *(const half8v*)(pa + k0);
#pragma unroll
        for (int ni = 0; ni < 4; ++ni) {
            half8v b = *(const half8v*)(pb + (size_t)ni * 16 * 1024 + k0);
            acc[ni] = __builtin_amdgcn_mfma_f32_16x16x32_f16(a, b, acc[ni], 0, 0, 0);
        }
    }

    const int row0 = w * 16 + (l >> 4) * 4;
    const int col0 = bx * 64 + (l & 15);
#pragma unroll
    for (int ni = 0; ni < 4; ++ni) {
        int col = col0 + ni * 16;
        float bb = bias[col];
#pragma unroll
        for (int r = 0; r < 4; ++r) {
            float v = acc[ni][r] + bb;
            v = v > 0.f ? v : 0.01f * v;
            if (mode == 0) out16[(size_t)(row0 + r) * 1024 + col] = (_Float16)v;
            else out32[(size_t)(row0 + r) * 1024 + col] = v;
        }
    }
}

// ---------------- fc3: one wave per output, f32 shfl reduction ----------------
__global__ void k_fc3(const float* __restrict__ z2, const float* __restrict__ W,
                      const float* __restrict__ b, float* __restrict__ out) {
    int gw = (blockIdx.x * blockDim.x + threadIdx.x) >> 6;
    int lane = threadIdx.x & 63;
    if (gw >= N_GRAPHS * NCLS) return;
    int row = gw / NCLS, col = gw - row * NCLS;
    float s = 0.f;
    for (int k = lane; k < 1024; k += 64) s += z2[(size_t)row * 1024 + k] * W[(size_t)k * NCLS + col];
#pragma unroll
    for (int o = 32; o; o >>= 1) s += __shfl_down(s, o);
    if (lane == 0) out[(size_t)row * NCLS + col] = s + b[col];
}

// ---------------- host orchestration ----------------
extern "C" void kernel_launch(void* const* d_in, const int* in_sizes, int n_in,
                              void* d_out, int out_size, void* d_ws, size_t ws_size,
                              hipStream_t stream) {
    const float* h = (const float*)d_in[0];
    const int* src = (const int*)d_in[1];
    const int* dst = (const int*)d_in[2];
    const int* gid = (const int*)d_in[3];

    const float *w_src[3], *b_src[3], *w_dst[3], *b_dst[3], *attn[3], *bias[3], *gamma[3], *beta[3];
    for (int l = 0; l < 3; ++l) {
        int base = 4 + l * 8;
        w_src[l] = (const float*)d_in[base + 0];
        b_src[l] = (const float*)d_in[base + 1];
        w_dst[l] = (const float*)d_in[base + 2];
        b_dst[l] = (const float*)d_in[base + 3];
        attn[l]  = (const float*)d_in[base + 4];
        bias[l]  = (const float*)d_in[base + 5];
        gamma[l] = (const float*)d_in[base + 6];
        beta[l]  = (const float*)d_in[base + 7];
    }
    const float* fc1_w = (const float*)d_in[28];
    const float* fc1_b = (const float*)d_in[29];
    const float* fc2_w = (const float*)d_in[30];
    const float* fc2_b = (const float*)d_in[31];
    const float* fc3_w = (const float*)d_in[32];
    const float* fc3_b = (const float*)d_in[33];

    // workspace carve
    char* base = (char*)d_ws;
    size_t o = 0;
    auto carve = [&](size_t bytes) -> char* {
        char* p = base + o;
        o += (bytes + 255) & ~(size_t)255;
        return p;
    };
    _Float16* fs16 = (_Float16*)carve((size_t)N_NODES * F * 2);
    _Float16* fd16 = (_Float16*)carve((size_t)N_NODES * F * 2);
    _Float16* y16 = (_Float16*)carve((size_t)N_NODES * F * 2);
    float* x32 = (float*)carve((size_t)N_NODES * F * 4);   // layer-3 BN output for pool
    _Float16* xh = (_Float16*)carve((size_t)N_PAD * F * 2);
    _Float16* wsh = (_Float16*)carve((size_t)F * F * 2);
    _Float16* wdh = (_Float16*)carve((size_t)F * F * 2);
    _Float16* fc1h = (_Float16*)carve((size_t)F * F * 2);
    _Float16* fc2h = (_Float16*)carve((size_t)F * F * 2);
    int* cnt = (int*)carve((size_t)N_NODES * 4);
    int* off = (int*)carve((size_t)(N_NODES + 1) * 4);
    int* cursor = (int*)carve((size_t)N_NODES * 4);
    int* csr_e = (int*)carve((size_t)N_EDGES * 4);
    float* part = (float*)carve((size_t)BN_CHUNKS * 2 * F * 4);
    float* scale = (float*)carve(F * 4);
    float* shift = (float*)carve(F * 4);
    int* gstart = (int*)carve((N_GRAPHS + 1) * 4);
    _Float16* hg16 = (_Float16*)carve((size_t)N_GRAPHS * F * 2);
    _Float16* z1h = (_Float16*)carve((size_t)N_GRAPHS * F * 2);
    float* z2 = (float*)carve((size_t)N_GRAPHS * F * 4);
    (void)ws_size;

    // ---- CSR build (deterministic: buckets sorted by edge id) ----
    k_zero_i32<<<(N_NODES + 255) / 256, 256, 0, stream>>>(cnt, N_NODES);
    k_count<<<(N_EDGES + 255) / 256, 256, 0, stream>>>(dst, cnt);
    k_scan<<<1, 256, 0, stream>>>(cnt, off);
    k_copy_i32<<<(N_NODES + 255) / 256, 256, 0, stream>>>(cursor, off, N_NODES);
    k_fill<<<(N_EDGES + 255) / 256, 256, 0, stream>>>(dst, cursor, csr_e);
    k_sort_buckets<<<(N_NODES + 255) / 256, 256, 0, stream>>>(off, csr_e);
    k_gstart<<<1, 128, 0, stream>>>(gid, gstart);

    // ---- input conversion + pad-row zeroing + MLP weight conversion ----
    k_cvt_h<<<(N_PAD * 64 + 255) / 256, 256, 0, stream>>>(h, xh);
    k_zero_pad<<<((N_PAD - N_NODES) * F + 255) / 256, 256, 0, stream>>>(xh);
    k_cvt_w2<<<dim3(F / 32, F / 32, 2), 256, 0, stream>>>(fc1_w, fc1h, fc2_w, fc2h, F, F);

    // ---- 3 GATv2 + BN + lrelu layers ----
    const dim3 ggrid(8, N_PAD / 128);
    for (int l = 0; l < 3; ++l) {
        const int K = (l == 0) ? IN_F : F;
        const int Kp = (l == 0) ? 64 : F;
        k_cvt_w2<<<dim3(Kp / 32, F / 32, 2), 256, 0, stream>>>(w_src[l], wsh, w_dst[l], wdh, K, Kp);
        if (Kp == 64)
            k_gemm_dual<64><<<ggrid, 256, 0, stream>>>(xh, wsh, wdh, b_src[l], b_dst[l], fs16, fd16);
        else
            k_gemm_dual<1024><<<ggrid, 256, 0, stream>>>(xh, wsh, wdh, b_src[l], b_dst[l], fs16, fd16);
        k_gat<<<N_NODES, 128, 0, stream>>>(fs16, fd16, off, csr_e, src, attn[l], bias[l], y16);
        k_bnpart<<<BN_CHUNKS, 256, 0, stream>>>(y16, part);
        k_bnfin<<<F / 256, 256, 0, stream>>>(part, gamma[l], beta[l], scale, shift);
        k_bnapply<<<(N_NODES * (F / 4) + 255) / 256, 256, 0, stream>>>(
            y16, scale, shift, x32, xh, (l == 2) ? 1 : 0);
    }

    // ---- pool + MLP head (MFMA fc1/fc2, wave-reduce fc3) ----
    k_pool<<<dim3(4, N_GRAPHS), 256, 0, stream>>>(x32, gstart, hg16);
    k_mlp_mfma<<<16, 256, 0, stream>>>(hg16, fc1h, fc1_b, z1h, nullptr, 0);
    k_mlp_mfma<<<16, 256, 0, stream>>>(z1h, fc2h, fc2_b, nullptr, z2, 1);
    k_fc3<<<(N_GRAPHS * NCLS * 64 + 255) / 256, 256, 0, stream>>>(z2, fc3_w, fc3_b, (float*)d_out);
}

// Round 10
// 773.229 us; speedup vs baseline: 1.1383x; 1.0258x over previous
//
#include <hip/hip_runtime.h>
#include <math.h>

#define N_NODES 20000
#define N_PAD   20096            // 157 * 128
#define N_EDGES 100000
#define N_GRAPHS 64
#define IN_F 63
#define NHEAD 8
#define F 1024                   // NHEAD * HID
#define NCLS 18
#define BN_EPS 1e-5f
#define BN_CHUNKS 256

typedef __attribute__((ext_vector_type(8))) _Float16 half8v;  // 8 f16 (4 VGPRs)
typedef __attribute__((ext_vector_type(4))) _Float16 half4v;
typedef __attribute__((ext_vector_type(4))) float f32x4;

// ---------------- utility ----------------
__global__ void k_zero_i32(int* __restrict__ p, int n) {
    int i = blockIdx.x * blockDim.x + threadIdx.x;
    if (i < n) p[i] = 0;
}

// ---------------- CSR build over dst ----------------
__global__ void k_count(const int* __restrict__ dst, int* __restrict__ cnt) {
    int i = blockIdx.x * blockDim.x + threadIdx.x;
    if (i < N_EDGES) atomicAdd(&cnt[dst[i]], 1);
}

// exclusive scan over cnt -> off; also computes per-graph node starts (gstart)
__global__ void k_scan(const int* __restrict__ cnt, int* __restrict__ off,
                       const int* __restrict__ gid, int* __restrict__ gstart) {
    __shared__ int tsum[256];
    const int CH = (N_NODES + 255) / 256;
    int t = threadIdx.x;
    int s = 0;
    for (int i = 0; i < CH; ++i) {
        int idx = t * CH + i;
        if (idx < N_NODES) s += cnt[idx];
    }
    tsum[t] = s;
    __syncthreads();
    if (t == 0) {
        int acc = 0;
        for (int i = 0; i < 256; ++i) { int v = tsum[i]; tsum[i] = acc; acc += v; }
    }
    __syncthreads();
    int run = tsum[t];
    for (int i = 0; i < CH; ++i) {
        int idx = t * CH + i;
        if (idx < N_NODES) { off[idx] = run; run += cnt[idx]; }
    }
    if (t == 255) off[N_NODES] = run;
    // gstart: binary search per graph id (threads 0..N_GRAPHS)
    if (t <= N_GRAPHS) {
        int lo = 0, hi = N_NODES;
        while (lo < hi) {
            int mid = (lo + hi) >> 1;
            if (gid[mid] < t) lo = mid + 1; else hi = mid;
        }
        gstart[t] = lo;
    }
}

// fill CSR using a second zeroed counter (fcnt); deterministic after sort
__global__ void k_fill(const int* __restrict__ dst, const int* __restrict__ off,
                       int* __restrict__ fcnt, int* __restrict__ csr_e) {
    int i = blockIdx.x * blockDim.x + threadIdx.x;
    if (i < N_EDGES) {
        int d = dst[i];
        int p = atomicAdd(&fcnt[d], 1);
        csr_e[off[d] + p] = i;
    }
}

__global__ void k_sort_buckets(const int* __restrict__ off, int* __restrict__ csr_e) {
    int n = blockIdx.x * blockDim.x + threadIdx.x;
    if (n >= N_NODES) return;
    int b = off[n], e = off[n + 1];
    for (int i = b + 1; i < e; ++i) {
        int v = csr_e[i];
        int j = i - 1;
        while (j >= b && csr_e[j] > v) { csr_e[j + 1] = csr_e[j]; --j; }
        csr_e[j + 1] = v;
    }
}

// ---------------- conversions for f16 GEMM ----------------
__global__ void k_cvt_h(const float* __restrict__ h, _Float16* __restrict__ xh) {
    int idx = blockIdx.x * 256 + threadIdx.x;
    if (idx >= N_PAD * 64) return;
    int m = idx >> 6, k = idx & 63;
    float v = (m < N_NODES && k < IN_F) ? h[m * IN_F + k] : 0.f;
    xh[idx] = (_Float16)v;
}

__global__ void k_zero_pad(_Float16* __restrict__ xh) {
    int idx = blockIdx.x * 256 + threadIdx.x;
    const int total = (N_PAD - N_NODES) * F;
    if (idx < total) xh[(size_t)N_NODES * F + idx] = (_Float16)0.f;
}

// W [K][1024] f32 -> W^T [1024][Kpad] f16; two matrices per launch (grid.z)
__global__ void k_cvt_w2(const float* __restrict__ W0, _Float16* __restrict__ o0,
                         const float* __restrict__ W1, _Float16* __restrict__ o1,
                         int K, int Kpad) {
    const float* W = blockIdx.z ? W1 : W0;
    _Float16* wh = blockIdx.z ? o1 : o0;
    __shared__ float t[32][33];
    int kt = blockIdx.x * 32, nt = blockIdx.y * 32;
    int tx = threadIdx.x & 31, ty = threadIdx.x >> 5;
#pragma unroll
    for (int j = 0; j < 4; ++j) {
        int k = kt + ty + j * 8;
        t[ty + j * 8][tx] = (k < K) ? W[(size_t)k * F + nt + tx] : 0.f;
    }
    __syncthreads();
#pragma unroll
    for (int j = 0; j < 4; ++j) {
        int n = nt + ty + j * 8;
        wh[(size_t)n * Kpad + kt + tx] = (_Float16)t[tx][ty + j * 8];
    }
}

// six K=1024 weight matrices in one launch (grid.z = 6)
__global__ void k_cvt_w6(const float* __restrict__ a0, _Float16* __restrict__ b0,
                         const float* __restrict__ a1, _Float16* __restrict__ b1,
                         const float* __restrict__ a2, _Float16* __restrict__ b2,
                         const float* __restrict__ a3, _Float16* __restrict__ b3,
                         const float* __restrict__ a4, _Float16* __restrict__ b4,
                         const float* __restrict__ a5, _Float16* __restrict__ b5) {
    const float* W; _Float16* wh;
    switch (blockIdx.z) {
        case 0: W = a0; wh = b0; break;
        case 1: W = a1; wh = b1; break;
        case 2: W = a2; wh = b2; break;
        case 3: W = a3; wh = b3; break;
        case 4: W = a4; wh = b4; break;
        default: W = a5; wh = b5; break;
    }
    __shared__ float t[32][33];
    int kt = blockIdx.x * 32, nt = blockIdx.y * 32;
    int tx = threadIdx.x & 31, ty = threadIdx.x >> 5;
#pragma unroll
    for (int j = 0; j < 4; ++j) {
        int k = kt + ty + j * 8;
        t[ty + j * 8][tx] = W[(size_t)k * F + nt + tx];
    }
    __syncthreads();
#pragma unroll
    for (int j = 0; j < 4; ++j) {
        int n = nt + ty + j * 8;
        wh[(size_t)n * F + kt + tx] = (_Float16)t[tx][ty + j * 8];
    }
}

// ---------------- fused dual f16 MFMA GEMM, BK=64, XOR-swizzled LDS (r6 exact) ----
// fs16 = A@Ws + bs AND fd16 = A@Wd + bd (f16 outputs). Tiles [128 rows][64 halves]
// (128B rows). Swizzle (both-sides): stage-time global chunk permutation
// chunk' = chunk ^ (row&7) (per-lane ((l&7)^(l>>3))<<3), read-time byte ^ ((l&7)<<4).
// Verified 0 bank conflicts (rounds 5,6). grid = (8, N_PAD/128), 256 threads.
#define AS1C(p) ((const __attribute__((address_space(1))) void*)(p))
#define AS3(p)  ((__attribute__((address_space(3))) void*)(p))

__launch_bounds__(256, 2)
__global__ void k_gemm_dual(const _Float16* __restrict__ A,
                            const _Float16* __restrict__ Bs, const _Float16* __restrict__ Bd,
                            const float* __restrict__ bias_s, const float* __restrict__ bias_d,
                            _Float16* __restrict__ Cs, _Float16* __restrict__ Cd, int Kpad) {
    __shared__ _Float16 lds[24576];   // 3 tiles x [128][64] f16 = 48 KiB
    const int tid = threadIdx.x;
    const int l = tid & 63, w = tid >> 6;

    // XCD-aware bijective swizzle: nwg = 8*157 = 1256, 1256 % 8 == 0
    const int orig = blockIdx.y * 8 + blockIdx.x;
    const int wg = (orig & 7) * (N_PAD / 128) + (orig >> 3);
    const int by = wg >> 3, bx = wg & 7;

    // --- staging: wave w stages rows [w*32, w*32+32), 4 loads x 8 rows per tile ---
    const int grow = w * 32 + (l >> 3);
    const int gcol = ((l & 7) ^ (l >> 3)) << 3;         // swizzled 16B chunk (halves)
    const size_t rstep = (size_t)8 * Kpad;
    const _Float16* gA = A + (size_t)(by * 128 + grow) * Kpad + gcol;
    const _Float16* gBs = Bs + (size_t)(bx * 128 + grow) * Kpad + gcol;
    const _Float16* gBd = Bd + (size_t)(bx * 128 + grow) * Kpad + gcol;
    char* sA = (char*)lds + w * 4096;
    char* sBs = (char*)lds + 16384 + w * 4096;
    char* sBd = (char*)lds + 32768 + w * 4096;

    // --- fragment coords: wave (wr,wc) owns a 64x64 sub-tile of each output ---
    const int wr = (w >> 1) * 64, wc = (w & 1) * 64;
    const int frow = l & 15;
    const int swz = (l & 7) << 4;                       // read-side XOR (row&7 == l&7)
    const int kbase = (l >> 4) * 16;

    f32x4 accS[4][4], accD[4][4];
    const f32x4 fzero = {0.f, 0.f, 0.f, 0.f};
#pragma unroll
    for (int i = 0; i < 4; ++i)
#pragma unroll
        for (int j = 0; j < 4; ++j) { accS[i][j] = fzero; accD[i][j] = fzero; }

    for (int k0 = 0; k0 < Kpad; k0 += 64) {
#pragma unroll
        for (int j = 0; j < 4; ++j) {
            __builtin_amdgcn_global_load_lds(AS1C(gA + j * rstep), AS3(sA + j * 1024), 16, 0, 0);
            __builtin_amdgcn_global_load_lds(AS1C(gBs + j * rstep), AS3(sBs + j * 1024), 16, 0, 0);
            __builtin_amdgcn_global_load_lds(AS1C(gBd + j * rstep), AS3(sBd + j * 1024), 16, 0, 0);
        }
        gA += 64; gBs += 64; gBd += 64;
        __syncthreads();

#pragma unroll
        for (int kk = 0; kk < 2; ++kk) {
            const int kb = (kk * 64 + kbase) ^ swz;
            half8v a[4];
#pragma unroll
            for (int mi = 0; mi < 4; ++mi) {
                int row = wr + mi * 16 + frow;
                a[mi] = *(const half8v*)((const char*)lds + row * 128 + kb);
            }
#pragma unroll
            for (int ni = 0; ni < 4; ++ni) {
                int rowb = wc + ni * 16 + frow;
                half8v bs = *(const half8v*)((const char*)lds + 16384 + rowb * 128 + kb);
                half8v bd = *(const half8v*)((const char*)lds + 32768 + rowb * 128 + kb);
#pragma unroll
                for (int mi = 0; mi < 4; ++mi) {
                    accS[mi][ni] = __builtin_amdgcn_mfma_f32_16x16x32_f16(a[mi], bs, accS[mi][ni], 0, 0, 0);
                    accD[mi][ni] = __builtin_amdgcn_mfma_f32_16x16x32_f16(a[mi], bd, accD[mi][ni], 0, 0, 0);
                }
            }
        }
        __syncthreads();
    }

    // epilogue: C/D layout col = lane&15, row = (lane>>4)*4 + reg; f16 stores
    const int crow0 = by * 128 + wr + (l >> 4) * 4;
    const int ccol = bx * 128 + wc + (l & 15);
    float bS[4], bD[4];
#pragma unroll
    for (int ni = 0; ni < 4; ++ni) { bS[ni] = bias_s[ccol + ni * 16]; bD[ni] = bias_d[ccol + ni * 16]; }
#pragma unroll
    for (int mi = 0; mi < 4; ++mi) {
#pragma unroll
        for (int r = 0; r < 4; ++r) {
            int row = crow0 + mi * 16 + r;
            if (row < N_NODES) {
#pragma unroll
                for (int ni = 0; ni < 4; ++ni) {
                    int col = ccol + ni * 16;
                    Cs[(size_t)row * F + col] = (_Float16)(accS[mi][ni][r] + bS[ni]);
                    Cd[(size_t)row * F + col] = (_Float16)(accD[mi][ni][r] + bD[ni]);
                }
            }
        }
    }
}

// ---------------- fused GATv2 edge+softmax+aggregate (online softmax, f16 io) ----
// 128 threads/block, one block per dst node; 8 f16 per thread (16B/lane).
__launch_bounds__(128)
__global__ void k_gat(const _Float16* __restrict__ fs, const _Float16* __restrict__ fd,
                      const int* __restrict__ off, const int* __restrict__ csr_e,
                      const int* __restrict__ src, const float* __restrict__ attn,
                      const float* __restrict__ bias, _Float16* __restrict__ y16) {
    __shared__ int s_src[128];
    const int n = blockIdx.x;
    const int t = threadIdx.x;
    const int b = off[n], e = off[n + 1];

    half8v fdv8 = *(const half8v*)(fd + (size_t)n * F + t * 8);
    float fdv[8], av[8];
    const float4 a0 = *(const float4*)(attn + (t >> 4) * 128 + (t & 15) * 8);
    const float4 a1 = *(const float4*)(attn + (t >> 4) * 128 + (t & 15) * 8 + 4);
    av[0] = a0.x; av[1] = a0.y; av[2] = a0.z; av[3] = a0.w;
    av[4] = a1.x; av[5] = a1.y; av[6] = a1.z; av[7] = a1.w;
#pragma unroll
    for (int j = 0; j < 8; ++j) fdv[j] = (float)fdv8[j];

    float m = -1e30f, den = 0.f;
    float acc[8] = {0.f, 0.f, 0.f, 0.f, 0.f, 0.f, 0.f, 0.f};

    for (int c0 = b; c0 < e; c0 += 128) {
        int ncur = e - c0; if (ncur > 128) ncur = 128;
        __syncthreads();
        if (t < ncur) s_src[t] = src[csr_e[c0 + t]];
        __syncthreads();
        for (int i = 0; i < ncur; ++i) {
            int s = s_src[i];
            half8v fsv8 = *(const half8v*)(fs + (size_t)s * F + t * 8);
            float f[8];
            float p = 0.f;
#pragma unroll
            for (int j = 0; j < 8; ++j) {
                f[j] = (float)fsv8[j];
                float v = f[j] + fdv[j];
                v = v > 0.f ? v : 0.2f * v;
                p += v * av[j];
            }
            p += __shfl_xor(p, 1);
            p += __shfl_xor(p, 2);
            p += __shfl_xor(p, 4);
            p += __shfl_xor(p, 8);     // 16-lane head group holds full score
            float mn = fmaxf(m, p);
            float so = __expf(m - mn);
            float wexp = __expf(p - mn);
            den = den * so + wexp;
#pragma unroll
            for (int j = 0; j < 8; ++j) acc[j] = acc[j] * so + wexp * f[j];
            m = mn;
        }
    }
    float inv = (e > b) ? 1.f / den : 0.f;
    const float4 b0 = *(const float4*)(bias + t * 8);
    const float4 b1 = *(const float4*)(bias + t * 8 + 4);
    float bb[8] = {b0.x, b0.y, b0.z, b0.w, b1.x, b1.y, b1.z, b1.w};
    half8v o;
#pragma unroll
    for (int j = 0; j < 8; ++j) o[j] = (_Float16)(acc[j] * inv + bb[j]);
    *(half8v*)(y16 + (size_t)n * F + t * 8) = o;
}

// ---------------- BatchNorm (2-stage deterministic) + lrelu, f16 io ----------------
__global__ void k_bnpart(const _Float16* __restrict__ y16, float* __restrict__ part) {
    const int ROWS = (N_NODES + BN_CHUNKS - 1) / BN_CHUNKS;
    int blk = blockIdx.x;
    int t = threadIdx.x;
    int r0 = blk * ROWS;
    int r1 = r0 + ROWS; if (r1 > N_NODES) r1 = N_NODES;
    float sx = 0.f, sy = 0.f, sz = 0.f, sw = 0.f;
    float qx = 0.f, qy = 0.f, qz = 0.f, qw = 0.f;
    for (int r = r0; r < r1; ++r) {
        half4v v = *(const half4v*)(y16 + (size_t)r * F + t * 4);
        float vx = (float)v.x, vy = (float)v.y, vz = (float)v.z, vw = (float)v.w;
        sx += vx; sy += vy; sz += vz; sw += vw;
        qx += vx * vx; qy += vy * vy; qz += vz * vz; qw += vw * vw;
    }
    float4 s4; s4.x = sx; s4.y = sy; s4.z = sz; s4.w = sw;
    float4 q4; q4.x = qx; q4.y = qy; q4.z = qz; q4.w = qw;
    *(float4*)(part + (size_t)blk * (2 * F) + t * 4) = s4;
    *(float4*)(part + (size_t)blk * (2 * F) + F + t * 4) = q4;
}

__global__ void k_bnfin(const float* __restrict__ part, const float* __restrict__ gamma,
                        const float* __restrict__ beta, float* __restrict__ scale,
                        float* __restrict__ shift) {
    int c = blockIdx.x * blockDim.x + threadIdx.x;
    if (c >= F) return;
    float s = 0.f, q = 0.f;
    for (int b = 0; b < BN_CHUNKS; ++b) {
        s += part[(size_t)b * (2 * F) + c];
        q += part[(size_t)b * (2 * F) + F + c];
    }
    float mu = s / (float)N_NODES;
    float var = q / (float)N_NODES - mu * mu;
    float sc = gamma[c] * rsqrtf(var + BN_EPS);
    scale[c] = sc;
    shift[c] = beta[c] - mu * sc;
}

// BN+lrelu from f16 y -> f16 xh (GEMM input for next layer / pool input for layer 3)
__global__ void k_bnapply(const _Float16* __restrict__ y16, const float* __restrict__ scale,
                          const float* __restrict__ shift, _Float16* __restrict__ xh) {
    int i = blockIdx.x * blockDim.x + threadIdx.x;
    if (i >= N_NODES * (F / 4)) return;
    int c4 = (i & (F / 4 - 1)) * 4;
    half4v v = ((const half4v*)y16)[i];
    float4 o;
    o.x = (float)v.x * scale[c4 + 0] + shift[c4 + 0];
    o.y = (float)v.y * scale[c4 + 1] + shift[c4 + 1];
    o.z = (float)v.z * scale[c4 + 2] + shift[c4 + 2];
    o.w = (float)v.w * scale[c4 + 3] + shift[c4 + 3];
    o.x = o.x > 0.f ? o.x : 0.01f * o.x;
    o.y = o.y > 0.f ? o.y : 0.01f * o.y;
    o.z = o.z > 0.f ? o.z : 0.01f * o.z;
    o.w = o.w > 0.f ? o.w : 0.01f * o.w;
    half4v h4;
    h4.x = (_Float16)o.x; h4.y = (_Float16)o.y;
    h4.z = (_Float16)o.z; h4.w = (_Float16)o.w;
    *(half4v*)&xh[(size_t)i * 4] = h4;
}

// ---------------- avg pool per graph (f16 in -> f16 out) ----------------
__global__ void k_pool(const _Float16* __restrict__ x16, const int* __restrict__ gstart,
                       _Float16* __restrict__ hg16) {
    int g = blockIdx.y;
    int col = blockIdx.x * 256 + threadIdx.x;
    int r0 = gstart[g], r1 = gstart[g + 1];
    float s = 0.f;
    for (int r = r0; r < r1; ++r) s += (float)x16[(size_t)r * F + col];
    float inv = (r1 > r0) ? 1.f / (float)(r1 - r0) : 0.f;
    hg16[(size_t)g * F + col] = (_Float16)(s * inv);
}

// ---------------- MLP fc1/fc2: f16 MFMA GEMM, M=64, N=K=1024 ----------------
__launch_bounds__(256)
__global__ void k_mlp_mfma(const _Float16* __restrict__ A16, const _Float16* __restrict__ Bt,
                           const float* __restrict__ bias, _Float16* __restrict__ out16,
                           float* __restrict__ out32, int mode) {
    const int l = threadIdx.x & 63, w = threadIdx.x >> 6;
    const int bx = blockIdx.x;
    const int fko = (l >> 4) * 8;

    const _Float16* pa = A16 + (size_t)(w * 16 + (l & 15)) * 1024 + fko;
    const _Float16* pb = Bt + (size_t)(bx * 64 + (l & 15)) * 1024 + fko;

    f32x4 acc[4];
    const f32x4 fzero = {0.f, 0.f, 0.f, 0.f};
#pragma unroll
    for (int ni = 0; ni < 4; ++ni) acc[ni] = fzero;

#pragma unroll 4
    for (int k0 = 0; k0 < 1024; k0 += 32) {
        half8v a = *(const half8v*)(pa + k0);
#pragma unroll
        for (int ni = 0; ni < 4; ++ni) {
            half8v b = *(const half8v*)(pb + (size_t)ni * 16 * 1024 + k0);
            acc[ni] = __builtin_amdgcn_mfma_f32_16x16x32_f16(a, b, acc[ni], 0, 0, 0);
        }
    }

    const int row0 = w * 16 + (l >> 4) * 4;
    const int col0 = bx * 64 + (l & 15);
#pragma unroll
    for (int ni = 0; ni < 4; ++ni) {
        int col = col0 + ni * 16;
        float bb = bias[col];
#pragma unroll
        for (int r = 0; r < 4; ++r) {
            float v = acc[ni][r] + bb;
            v = v > 0.f ? v : 0.01f * v;
            if (mode == 0) out16[(size_t)(row0 + r) * 1024 + col] = (_Float16)v;
            else out32[(size_t)(row0 + r) * 1024 + col] = v;
        }
    }
}

// ---------------- fc3: one wave per output, f32 shfl reduction ----------------
__global__ void k_fc3(const float* __restrict__ z2, const float* __restrict__ W,
                      const float* __restrict__ b, float* __restrict__ out) {
    int gw = (blockIdx.x * blockDim.x + threadIdx.x) >> 6;
    int lane = threadIdx.x & 63;
    if (gw >= N_GRAPHS * NCLS) return;
    int row = gw / NCLS, col = gw - row * NCLS;
    float s = 0.f;
    for (int k = lane; k < 1024; k += 64) s += z2[(size_t)row * 1024 + k] * W[(size_t)k * NCLS + col];
#pragma unroll
    for (int o = 32; o; o >>= 1) s += __shfl_down(s, o);
    if (lane == 0) out[(size_t)row * NCLS + col] = s + b[col];
}

// ---------------- host orchestration ----------------
extern "C" void kernel_launch(void* const* d_in, const int* in_sizes, int n_in,
                              void* d_out, int out_size, void* d_ws, size_t ws_size,
                              hipStream_t stream) {
    const float* h = (const float*)d_in[0];
    const int* src = (const int*)d_in[1];
    const int* dst = (const int*)d_in[2];
    const int* gid = (const int*)d_in[3];

    const float *w_src[3], *b_src[3], *w_dst[3], *b_dst[3], *attn[3], *bias[3], *gamma[3], *beta[3];
    for (int l = 0; l < 3; ++l) {
        int base = 4 + l * 8;
        w_src[l] = (const float*)d_in[base + 0];
        b_src[l] = (const float*)d_in[base + 1];
        w_dst[l] = (const float*)d_in[base + 2];
        b_dst[l] = (const float*)d_in[base + 3];
        attn[l]  = (const float*)d_in[base + 4];
        bias[l]  = (const float*)d_in[base + 5];
        gamma[l] = (const float*)d_in[base + 6];
        beta[l]  = (const float*)d_in[base + 7];
    }
    const float* fc1_w = (const float*)d_in[28];
    const float* fc1_b = (const float*)d_in[29];
    const float* fc2_w = (const float*)d_in[30];
    const float* fc2_b = (const float*)d_in[31];
    const float* fc3_w = (const float*)d_in[32];
    const float* fc3_b = (const float*)d_in[33];

    // workspace carve
    char* base = (char*)d_ws;
    size_t o = 0;
    auto carve = [&](size_t bytes) -> char* {
        char* p = base + o;
        o += (bytes + 255) & ~(size_t)255;
        return p;
    };
    _Float16* fs16 = (_Float16*)carve((size_t)N_NODES * F * 2);
    _Float16* fd16 = (_Float16*)carve((size_t)N_NODES * F * 2);
    _Float16* y16 = (_Float16*)carve((size_t)N_NODES * F * 2);
    _Float16* xh = (_Float16*)carve((size_t)N_PAD * F * 2);
    _Float16* w1s = (_Float16*)carve((size_t)F * 64 * 2);
    _Float16* w1d = (_Float16*)carve((size_t)F * 64 * 2);
    _Float16* w2s = (_Float16*)carve((size_t)F * F * 2);
    _Float16* w2d = (_Float16*)carve((size_t)F * F * 2);
    _Float16* w3s = (_Float16*)carve((size_t)F * F * 2);
    _Float16* w3d = (_Float16*)carve((size_t)F * F * 2);
    _Float16* fc1h = (_Float16*)carve((size_t)F * F * 2);
    _Float16* fc2h = (_Float16*)carve((size_t)F * F * 2);
    int* cnt = (int*)carve((size_t)2 * N_NODES * 4);      // [cnt | fill-cursor]
    int* fcnt = cnt + N_NODES;
    int* off = (int*)carve((size_t)(N_NODES + 1) * 4);
    int* csr_e = (int*)carve((size_t)N_EDGES * 4);
    float* part = (float*)carve((size_t)BN_CHUNKS * 2 * F * 4);
    float* scale = (float*)carve(F * 4);
    float* shift = (float*)carve(F * 4);
    int* gstart = (int*)carve((N_GRAPHS + 1) * 4);
    _Float16* hg16 = (_Float16*)carve((size_t)N_GRAPHS * F * 2);
    _Float16* z1h = (_Float16*)carve((size_t)N_GRAPHS * F * 2);
    float* z2 = (float*)carve((size_t)N_GRAPHS * F * 4);
    (void)ws_size;

    // ---- CSR build (deterministic: buckets sorted by edge id) ----
    k_zero_i32<<<(2 * N_NODES + 255) / 256, 256, 0, stream>>>(cnt, 2 * N_NODES);
    k_count<<<(N_EDGES + 255) / 256, 256, 0, stream>>>(dst, cnt);
    k_scan<<<1, 256, 0, stream>>>(cnt, off, gid, gstart);
    k_fill<<<(N_EDGES + 255) / 256, 256, 0, stream>>>(dst, off, fcnt, csr_e);
    k_sort_buckets<<<(N_NODES + 255) / 256, 256, 0, stream>>>(off, csr_e);

    // ---- input conversion + all weight conversions up-front ----
    k_cvt_h<<<(N_PAD * 64 + 255) / 256, 256, 0, stream>>>(h, xh);
    k_zero_pad<<<((N_PAD - N_NODES) * F + 255) / 256, 256, 0, stream>>>(xh);
    k_cvt_w2<<<dim3(2, F / 32, 2), 256, 0, stream>>>(w_src[0], w1s, w_dst[0], w1d, IN_F, 64);
    k_cvt_w6<<<dim3(F / 32, F / 32, 6), 256, 0, stream>>>(
        w_src[1], w2s, w_dst[1], w2d, w_src[2], w3s, w_dst[2], w3d, fc1_w, fc1h, fc2_w, fc2h);

    // ---- 3 GATv2 + BN + lrelu layers ----
    const dim3 ggrid(8, N_PAD / 128);
    const _Float16* ws16[3] = {w1s, w2s, w3s};
    const _Float16* wd16[3] = {w1d, w2d, w3d};
    for (int l = 0; l < 3; ++l) {
        const int Kp = (l == 0) ? 64 : F;
        k_gemm_dual<<<ggrid, 256, 0, stream>>>(xh, ws16[l], wd16[l], b_src[l], b_dst[l],
                                               fs16, fd16, Kp);
        k_gat<<<N_NODES, 128, 0, stream>>>(fs16, fd16, off, csr_e, src, attn[l], bias[l], y16);
        k_bnpart<<<BN_CHUNKS, 256, 0, stream>>>(y16, part);
        k_bnfin<<<F / 256, 256, 0, stream>>>(part, gamma[l], beta[l], scale, shift);
        k_bnapply<<<(N_NODES * (F / 4) + 255) / 256, 256, 0, stream>>>(y16, scale, shift, xh);
    }

    // ---- pool + MLP head (MFMA fc1/fc2, wave-reduce fc3) ----
    k_pool<<<dim3(4, N_GRAPHS), 256, 0, stream>>>(xh, gstart, hg16);
    k_mlp_mfma<<<16, 256, 0, stream>>>(hg16, fc1h, fc1_b, z1h, nullptr, 0);
    k_mlp_mfma<<<16, 256, 0, stream>>>(z1h, fc2h, fc2_b, nullptr, z2, 1);
    k_fc3<<<(N_GRAPHS * NCLS * 64 + 255) / 256, 256, 0, stream>>>(z2, fc3_w, fc3_b, (float*)d_out);
}

// Round 11
// 754.369 us; speedup vs baseline: 1.1668x; 1.0250x over previous
//
#include <hip/hip_runtime.h>
#include <math.h>

#define N_NODES 20000
#define N_PAD   20096            // 157 * 128
#define N_EDGES 100000
#define N_GRAPHS 64
#define IN_F 63
#define NHEAD 8
#define F 1024                   // NHEAD * HID
#define NCLS 18
#define BN_EPS 1e-5f
#define BN_CHUNKS 256

typedef __attribute__((ext_vector_type(8))) _Float16 half8v;  // 8 f16 (4 VGPRs)
typedef __attribute__((ext_vector_type(4))) _Float16 half4v;
typedef __attribute__((ext_vector_type(4))) float f32x4;

// ---------------- utility ----------------
__global__ void k_zero_i32(int* __restrict__ p, int n) {
    int i = blockIdx.x * blockDim.x + threadIdx.x;
    if (i < n) p[i] = 0;
}

// ---------------- CSR build over dst ----------------
__global__ void k_count(const int* __restrict__ dst, int* __restrict__ cnt) {
    int i = blockIdx.x * blockDim.x + threadIdx.x;
    if (i < N_EDGES) atomicAdd(&cnt[dst[i]], 1);
}

// exclusive scan over cnt -> off; also computes per-graph node starts (gstart)
__global__ void k_scan(const int* __restrict__ cnt, int* __restrict__ off,
                       const int* __restrict__ gid, int* __restrict__ gstart) {
    __shared__ int tsum[256];
    const int CH = (N_NODES + 255) / 256;
    int t = threadIdx.x;
    int s = 0;
    for (int i = 0; i < CH; ++i) {
        int idx = t * CH + i;
        if (idx < N_NODES) s += cnt[idx];
    }
    tsum[t] = s;
    __syncthreads();
    if (t == 0) {
        int acc = 0;
        for (int i = 0; i < 256; ++i) { int v = tsum[i]; tsum[i] = acc; acc += v; }
    }
    __syncthreads();
    int run = tsum[t];
    for (int i = 0; i < CH; ++i) {
        int idx = t * CH + i;
        if (idx < N_NODES) { off[idx] = run; run += cnt[idx]; }
    }
    if (t == 255) off[N_NODES] = run;
    if (t <= N_GRAPHS) {
        int lo = 0, hi = N_NODES;
        while (lo < hi) {
            int mid = (lo + hi) >> 1;
            if (gid[mid] < t) lo = mid + 1; else hi = mid;
        }
        gstart[t] = lo;
    }
}

// fill CSR using a second zeroed counter (fcnt); deterministic after sort
__global__ void k_fill(const int* __restrict__ dst, const int* __restrict__ off,
                       int* __restrict__ fcnt, int* __restrict__ csr_e) {
    int i = blockIdx.x * blockDim.x + threadIdx.x;
    if (i < N_EDGES) {
        int d = dst[i];
        int p = atomicAdd(&fcnt[d], 1);
        csr_e[off[d] + p] = i;
    }
}

__global__ void k_sort_buckets(const int* __restrict__ off, int* __restrict__ csr_e) {
    int n = blockIdx.x * blockDim.x + threadIdx.x;
    if (n >= N_NODES) return;
    int b = off[n], e = off[n + 1];
    for (int i = b + 1; i < e; ++i) {
        int v = csr_e[i];
        int j = i - 1;
        while (j >= b && csr_e[j] > v) { csr_e[j + 1] = csr_e[j]; --j; }
        csr_e[j + 1] = v;
    }
}

// ---------------- conversions for f16 GEMM ----------------
__global__ void k_cvt_h(const float* __restrict__ h, _Float16* __restrict__ xh) {
    int idx = blockIdx.x * 256 + threadIdx.x;
    if (idx >= N_PAD * 64) return;
    int m = idx >> 6, k = idx & 63;
    float v = (m < N_NODES && k < IN_F) ? h[m * IN_F + k] : 0.f;
    xh[idx] = (_Float16)v;
}

__global__ void k_zero_pad(_Float16* __restrict__ xh) {
    int idx = blockIdx.x * 256 + threadIdx.x;
    const int total = (N_PAD - N_NODES) * F;
    if (idx < total) xh[(size_t)N_NODES * F + idx] = (_Float16)0.f;
}

// W [K][1024] f32 -> W^T [1024][Kpad] f16; two matrices per launch (grid.z)
__global__ void k_cvt_w2(const float* __restrict__ W0, _Float16* __restrict__ o0,
                         const float* __restrict__ W1, _Float16* __restrict__ o1,
                         int K, int Kpad) {
    const float* W = blockIdx.z ? W1 : W0;
    _Float16* wh = blockIdx.z ? o1 : o0;
    __shared__ float t[32][33];
    int kt = blockIdx.x * 32, nt = blockIdx.y * 32;
    int tx = threadIdx.x & 31, ty = threadIdx.x >> 5;
#pragma unroll
    for (int j = 0; j < 4; ++j) {
        int k = kt + ty + j * 8;
        t[ty + j * 8][tx] = (k < K) ? W[(size_t)k * F + nt + tx] : 0.f;
    }
    __syncthreads();
#pragma unroll
    for (int j = 0; j < 4; ++j) {
        int n = nt + ty + j * 8;
        wh[(size_t)n * Kpad + kt + tx] = (_Float16)t[tx][ty + j * 8];
    }
}

// six K=1024 weight matrices in one launch (grid.z = 6)
__global__ void k_cvt_w6(const float* __restrict__ a0, _Float16* __restrict__ b0,
                         const float* __restrict__ a1, _Float16* __restrict__ b1,
                         const float* __restrict__ a2, _Float16* __restrict__ b2,
                         const float* __restrict__ a3, _Float16* __restrict__ b3,
                         const float* __restrict__ a4, _Float16* __restrict__ b4,
                         const float* __restrict__ a5, _Float16* __restrict__ b5) {
    const float* W; _Float16* wh;
    switch (blockIdx.z) {
        case 0: W = a0; wh = b0; break;
        case 1: W = a1; wh = b1; break;
        case 2: W = a2; wh = b2; break;
        case 3: W = a3; wh = b3; break;
        case 4: W = a4; wh = b4; break;
        default: W = a5; wh = b5; break;
    }
    __shared__ float t[32][33];
    int kt = blockIdx.x * 32, nt = blockIdx.y * 32;
    int tx = threadIdx.x & 31, ty = threadIdx.x >> 5;
#pragma unroll
    for (int j = 0; j < 4; ++j) {
        int k = kt + ty + j * 8;
        t[ty + j * 8][tx] = W[(size_t)k * F + nt + tx];
    }
    __syncthreads();
#pragma unroll
    for (int j = 0; j < 4; ++j) {
        int n = nt + ty + j * 8;
        wh[(size_t)n * F + kt + tx] = (_Float16)t[tx][ty + j * 8];
    }
}

// ---------------- fused dual f16 MFMA GEMM, BK=64, XOR-swizzled LDS (r6 exact) ----
#define AS1C(p) ((const __attribute__((address_space(1))) void*)(p))
#define AS3(p)  ((__attribute__((address_space(3))) void*)(p))

__launch_bounds__(256, 2)
__global__ void k_gemm_dual(const _Float16* __restrict__ A,
                            const _Float16* __restrict__ Bs, const _Float16* __restrict__ Bd,
                            const float* __restrict__ bias_s, const float* __restrict__ bias_d,
                            _Float16* __restrict__ Cs, _Float16* __restrict__ Cd, int Kpad) {
    __shared__ _Float16 lds[24576];   // 3 tiles x [128][64] f16 = 48 KiB
    const int tid = threadIdx.x;
    const int l = tid & 63, w = tid >> 6;

    // XCD-aware bijective swizzle: nwg = 8*157 = 1256, 1256 % 8 == 0
    const int orig = blockIdx.y * 8 + blockIdx.x;
    const int wg = (orig & 7) * (N_PAD / 128) + (orig >> 3);
    const int by = wg >> 3, bx = wg & 7;

    const int grow = w * 32 + (l >> 3);
    const int gcol = ((l & 7) ^ (l >> 3)) << 3;         // swizzled 16B chunk (halves)
    const size_t rstep = (size_t)8 * Kpad;
    const _Float16* gA = A + (size_t)(by * 128 + grow) * Kpad + gcol;
    const _Float16* gBs = Bs + (size_t)(bx * 128 + grow) * Kpad + gcol;
    const _Float16* gBd = Bd + (size_t)(bx * 128 + grow) * Kpad + gcol;
    char* sA = (char*)lds + w * 4096;
    char* sBs = (char*)lds + 16384 + w * 4096;
    char* sBd = (char*)lds + 32768 + w * 4096;

    const int wr = (w >> 1) * 64, wc = (w & 1) * 64;
    const int frow = l & 15;
    const int swz = (l & 7) << 4;                       // read-side XOR (row&7 == l&7)
    const int kbase = (l >> 4) * 16;

    f32x4 accS[4][4], accD[4][4];
    const f32x4 fzero = {0.f, 0.f, 0.f, 0.f};
#pragma unroll
    for (int i = 0; i < 4; ++i)
#pragma unroll
        for (int j = 0; j < 4; ++j) { accS[i][j] = fzero; accD[i][j] = fzero; }

    for (int k0 = 0; k0 < Kpad; k0 += 64) {
#pragma unroll
        for (int j = 0; j < 4; ++j) {
            __builtin_amdgcn_global_load_lds(AS1C(gA + j * rstep), AS3(sA + j * 1024), 16, 0, 0);
            __builtin_amdgcn_global_load_lds(AS1C(gBs + j * rstep), AS3(sBs + j * 1024), 16, 0, 0);
            __builtin_amdgcn_global_load_lds(AS1C(gBd + j * rstep), AS3(sBd + j * 1024), 16, 0, 0);
        }
        gA += 64; gBs += 64; gBd += 64;
        __syncthreads();

#pragma unroll
        for (int kk = 0; kk < 2; ++kk) {
            const int kb = (kk * 64 + kbase) ^ swz;
            half8v a[4];
#pragma unroll
            for (int mi = 0; mi < 4; ++mi) {
                int row = wr + mi * 16 + frow;
                a[mi] = *(const half8v*)((const char*)lds + row * 128 + kb);
            }
#pragma unroll
            for (int ni = 0; ni < 4; ++ni) {
                int rowb = wc + ni * 16 + frow;
                half8v bs = *(const half8v*)((const char*)lds + 16384 + rowb * 128 + kb);
                half8v bd = *(const half8v*)((const char*)lds + 32768 + rowb * 128 + kb);
#pragma unroll
                for (int mi = 0; mi < 4; ++mi) {
                    accS[mi][ni] = __builtin_amdgcn_mfma_f32_16x16x32_f16(a[mi], bs, accS[mi][ni], 0, 0, 0);
                    accD[mi][ni] = __builtin_amdgcn_mfma_f32_16x16x32_f16(a[mi], bd, accD[mi][ni], 0, 0, 0);
                }
            }
        }
        __syncthreads();
    }

    // epilogue: C/D layout col = lane&15, row = (lane>>4)*4 + reg; f16 stores
    const int crow0 = by * 128 + wr + (l >> 4) * 4;
    const int ccol = bx * 128 + wc + (l & 15);
    float bS[4], bD[4];
#pragma unroll
    for (int ni = 0; ni < 4; ++ni) { bS[ni] = bias_s[ccol + ni * 16]; bD[ni] = bias_d[ccol + ni * 16]; }
#pragma unroll
    for (int mi = 0; mi < 4; ++mi) {
#pragma unroll
        for (int r = 0; r < 4; ++r) {
            int row = crow0 + mi * 16 + r;
            if (row < N_NODES) {
#pragma unroll
                for (int ni = 0; ni < 4; ++ni) {
                    int col = ccol + ni * 16;
                    Cs[(size_t)row * F + col] = (_Float16)(accS[mi][ni][r] + bS[ni]);
                    Cd[(size_t)row * F + col] = (_Float16)(accD[mi][ni][r] + bD[ni]);
                }
            }
        }
    }
}

// ---------------- fused GATv2 edge+softmax+aggregate (online softmax, f16 io) ----
// 128 threads/block, one block per dst node; 8 f16 per thread (16B/lane).
// 1-deep prefetch: fs[s_src[i+1]] load issued before edge-i compute (T14).
__launch_bounds__(128)
__global__ void k_gat(const _Float16* __restrict__ fs, const _Float16* __restrict__ fd,
                      const int* __restrict__ off, const int* __restrict__ csr_e,
                      const int* __restrict__ src, const float* __restrict__ attn,
                      const float* __restrict__ bias, _Float16* __restrict__ y16) {
    __shared__ int s_src[128];
    const int n = blockIdx.x;
    const int t = threadIdx.x;
    const int b = off[n], e = off[n + 1];

    half8v fdv8 = *(const half8v*)(fd + (size_t)n * F + t * 8);
    float fdv[8], av[8];
    const float4 a0 = *(const float4*)(attn + (t >> 4) * 128 + (t & 15) * 8);
    const float4 a1 = *(const float4*)(attn + (t >> 4) * 128 + (t & 15) * 8 + 4);
    av[0] = a0.x; av[1] = a0.y; av[2] = a0.z; av[3] = a0.w;
    av[4] = a1.x; av[5] = a1.y; av[6] = a1.z; av[7] = a1.w;
#pragma unroll
    for (int j = 0; j < 8; ++j) fdv[j] = (float)fdv8[j];

    float m = -1e30f, den = 0.f;
    float acc[8] = {0.f, 0.f, 0.f, 0.f, 0.f, 0.f, 0.f, 0.f};

    for (int c0 = b; c0 < e; c0 += 128) {
        int ncur = e - c0; if (ncur > 128) ncur = 128;
        __syncthreads();
        if (t < ncur) s_src[t] = src[csr_e[c0 + t]];
        __syncthreads();
        half8v nxt = *(const half8v*)(fs + (size_t)s_src[0] * F + t * 8);
        for (int i = 0; i < ncur; ++i) {
            half8v cur = nxt;
            if (i + 1 < ncur)
                nxt = *(const half8v*)(fs + (size_t)s_src[i + 1] * F + t * 8);
            float f[8];
            float p = 0.f;
#pragma unroll
            for (int j = 0; j < 8; ++j) {
                f[j] = (float)cur[j];
                float v = f[j] + fdv[j];
                v = v > 0.f ? v : 0.2f * v;
                p += v * av[j];
            }
            p += __shfl_xor(p, 1);
            p += __shfl_xor(p, 2);
            p += __shfl_xor(p, 4);
            p += __shfl_xor(p, 8);     // 16-lane head group holds full score
            float mn = fmaxf(m, p);
            float so = __expf(m - mn);
            float wexp = __expf(p - mn);
            den = den * so + wexp;
#pragma unroll
            for (int j = 0; j < 8; ++j) acc[j] = acc[j] * so + wexp * f[j];
            m = mn;
        }
    }
    float inv = (e > b) ? 1.f / den : 0.f;
    const float4 b0 = *(const float4*)(bias + t * 8);
    const float4 b1 = *(const float4*)(bias + t * 8 + 4);
    float bb[8] = {b0.x, b0.y, b0.z, b0.w, b1.x, b1.y, b1.z, b1.w};
    half8v o;
#pragma unroll
    for (int j = 0; j < 8; ++j) o[j] = (_Float16)(acc[j] * inv + bb[j]);
    *(half8v*)(y16 + (size_t)n * F + t * 8) = o;
}

// ---------------- BatchNorm (2-stage deterministic) + lrelu, f16 io ----------------
__global__ void k_bnpart(const _Float16* __restrict__ y16, float* __restrict__ part) {
    const int ROWS = (N_NODES + BN_CHUNKS - 1) / BN_CHUNKS;
    int blk = blockIdx.x;
    int t = threadIdx.x;
    int r0 = blk * ROWS;
    int r1 = r0 + ROWS; if (r1 > N_NODES) r1 = N_NODES;
    float sx = 0.f, sy = 0.f, sz = 0.f, sw = 0.f;
    float qx = 0.f, qy = 0.f, qz = 0.f, qw = 0.f;
    for (int r = r0; r < r1; ++r) {
        half4v v = *(const half4v*)(y16 + (size_t)r * F + t * 4);
        float vx = (float)v.x, vy = (float)v.y, vz = (float)v.z, vw = (float)v.w;
        sx += vx; sy += vy; sz += vz; sw += vw;
        qx += vx * vx; qy += vy * vy; qz += vz * vz; qw += vw * vw;
    }
    float4 s4; s4.x = sx; s4.y = sy; s4.z = sz; s4.w = sw;
    float4 q4; q4.x = qx; q4.y = qy; q4.z = qz; q4.w = qw;
    *(float4*)(part + (size_t)blk * (2 * F) + t * 4) = s4;
    *(float4*)(part + (size_t)blk * (2 * F) + F + t * 4) = q4;
}

__global__ void k_bnfin(const float* __restrict__ part, const float* __restrict__ gamma,
                        const float* __restrict__ beta, float* __restrict__ scale,
                        float* __restrict__ shift) {
    int c = blockIdx.x * blockDim.x + threadIdx.x;
    if (c >= F) return;
    float s = 0.f, q = 0.f;
    for (int b = 0; b < BN_CHUNKS; ++b) {
        s += part[(size_t)b * (2 * F) + c];
        q += part[(size_t)b * (2 * F) + F + c];
    }
    float mu = s / (float)N_NODES;
    float var = q / (float)N_NODES - mu * mu;
    float sc = gamma[c] * rsqrtf(var + BN_EPS);
    scale[c] = sc;
    shift[c] = beta[c] - mu * sc;
}

// BN+lrelu from f16 y -> f16 xh (GEMM input for next layer; layers 1,2 only)
__global__ void k_bnapply(const _Float16* __restrict__ y16, const float* __restrict__ scale,
                          const float* __restrict__ shift, _Float16* __restrict__ xh) {
    int i = blockIdx.x * blockDim.x + threadIdx.x;
    if (i >= N_NODES * (F / 4)) return;
    int c4 = (i & (F / 4 - 1)) * 4;
    half4v v = ((const half4v*)y16)[i];
    float4 o;
    o.x = (float)v.x * scale[c4 + 0] + shift[c4 + 0];
    o.y = (float)v.y * scale[c4 + 1] + shift[c4 + 1];
    o.z = (float)v.z * scale[c4 + 2] + shift[c4 + 2];
    o.w = (float)v.w * scale[c4 + 3] + shift[c4 + 3];
    o.x = o.x > 0.f ? o.x : 0.01f * o.x;
    o.y = o.y > 0.f ? o.y : 0.01f * o.y;
    o.z = o.z > 0.f ? o.z : 0.01f * o.z;
    o.w = o.w > 0.f ? o.w : 0.01f * o.w;
    half4v h4;
    h4.x = (_Float16)o.x; h4.y = (_Float16)o.y;
    h4.z = (_Float16)o.z; h4.w = (_Float16)o.w;
    *(half4v*)&xh[(size_t)i * 4] = h4;
}

// ---------------- layer-3 fused BN+lrelu+avg-pool (y16 -> hg16) ----------------
__global__ void k_pool_bn(const _Float16* __restrict__ y16, const float* __restrict__ scale,
                          const float* __restrict__ shift, const int* __restrict__ gstart,
                          _Float16* __restrict__ hg16) {
    int g = blockIdx.y;
    int col = blockIdx.x * 256 + threadIdx.x;
    float sc = scale[col], sh = shift[col];
    int r0 = gstart[g], r1 = gstart[g + 1];
    float s = 0.f;
    for (int r = r0; r < r1; ++r) {
        float v = (float)y16[(size_t)r * F + col] * sc + sh;
        s += v > 0.f ? v : 0.01f * v;
    }
    float inv = (r1 > r0) ? 1.f / (float)(r1 - r0) : 0.f;
    hg16[(size_t)g * F + col] = (_Float16)(s * inv);
}

// ---------------- MLP fc1/fc2: f16 MFMA GEMM, M=64, N=K=1024 ----------------
__launch_bounds__(256)
__global__ void k_mlp_mfma(const _Float16* __restrict__ A16, const _Float16* __restrict__ Bt,
                           const float* __restrict__ bias, _Float16* __restrict__ out16,
                           float* __restrict__ out32, int mode) {
    const int l = threadIdx.x & 63, w = threadIdx.x >> 6;
    const int bx = blockIdx.x;
    const int fko = (l >> 4) * 8;

    const _Float16* pa = A16 + (size_t)(w * 16 + (l & 15)) * 1024 + fko;
    const _Float16* pb = Bt + (size_t)(bx * 64 + (l & 15)) * 1024 + fko;

    f32x4 acc[4];
    const f32x4 fzero = {0.f, 0.f, 0.f, 0.f};
#pragma unroll
    for (int ni = 0; ni < 4; ++ni) acc[ni] = fzero;

#pragma unroll 4
    for (int k0 = 0; k0 < 1024; k0 += 32) {
        half8v a = *(const half8v*)(pa + k0);
#pragma unroll
        for (int ni = 0; ni < 4; ++ni) {
            half8v b = *(const half8v*)(pb + (size_t)ni * 16 * 1024 + k0);
            acc[ni] = __builtin_amdgcn_mfma_f32_16x16x32_f16(a, b, acc[ni], 0, 0, 0);
        }
    }

    const int row0 = w * 16 + (l >> 4) * 4;
    const int col0 = bx * 64 + (l & 15);
#pragma unroll
    for (int ni = 0; ni < 4; ++ni) {
        int col = col0 + ni * 16;
        float bb = bias[col];
#pragma unroll
        for (int r = 0; r < 4; ++r) {
            float v = acc[ni][r] + bb;
            v = v > 0.f ? v : 0.01f * v;
            if (mode == 0) out16[(size_t)(row0 + r) * 1024 + col] = (_Float16)v;
            else out32[(size_t)(row0 + r) * 1024 + col] = v;
        }
    }
}

// ---------------- fc3: one wave per output, f32 shfl reduction ----------------
__global__ void k_fc3(const float* __restrict__ z2, const float* __restrict__ W,
                      const float* __restrict__ b, float* __restrict__ out) {
    int gw = (blockIdx.x * blockDim.x + threadIdx.x) >> 6;
    int lane = threadIdx.x & 63;
    if (gw >= N_GRAPHS * NCLS) return;
    int row = gw / NCLS, col = gw - row * NCLS;
    float s = 0.f;
    for (int k = lane; k < 1024; k += 64) s += z2[(size_t)row * 1024 + k] * W[(size_t)k * NCLS + col];
#pragma unroll
    for (int o = 32; o; o >>= 1) s += __shfl_down(s, o);
    if (lane == 0) out[(size_t)row * NCLS + col] = s + b[col];
}

// ---------------- host orchestration ----------------
extern "C" void kernel_launch(void* const* d_in, const int* in_sizes, int n_in,
                              void* d_out, int out_size, void* d_ws, size_t ws_size,
                              hipStream_t stream) {
    const float* h = (const float*)d_in[0];
    const int* src = (const int*)d_in[1];
    const int* dst = (const int*)d_in[2];
    const int* gid = (const int*)d_in[3];

    const float *w_src[3], *b_src[3], *w_dst[3], *b_dst[3], *attn[3], *bias[3], *gamma[3], *beta[3];
    for (int l = 0; l < 3; ++l) {
        int base = 4 + l * 8;
        w_src[l] = (const float*)d_in[base + 0];
        b_src[l] = (const float*)d_in[base + 1];
        w_dst[l] = (const float*)d_in[base + 2];
        b_dst[l] = (const float*)d_in[base + 3];
        attn[l]  = (const float*)d_in[base + 4];
        bias[l]  = (const float*)d_in[base + 5];
        gamma[l] = (const float*)d_in[base + 6];
        beta[l]  = (const float*)d_in[base + 7];
    }
    const float* fc1_w = (const float*)d_in[28];
    const float* fc1_b = (const float*)d_in[29];
    const float* fc2_w = (const float*)d_in[30];
    const float* fc2_b = (const float*)d_in[31];
    const float* fc3_w = (const float*)d_in[32];
    const float* fc3_b = (const float*)d_in[33];

    // workspace carve
    char* base = (char*)d_ws;
    size_t o = 0;
    auto carve = [&](size_t bytes) -> char* {
        char* p = base + o;
        o += (bytes + 255) & ~(size_t)255;
        return p;
    };
    _Float16* fs16 = (_Float16*)carve((size_t)N_NODES * F * 2);
    _Float16* fd16 = (_Float16*)carve((size_t)N_NODES * F * 2);
    _Float16* y16 = (_Float16*)carve((size_t)N_NODES * F * 2);
    _Float16* xh = (_Float16*)carve((size_t)N_PAD * F * 2);
    _Float16* w1s = (_Float16*)carve((size_t)F * 64 * 2);
    _Float16* w1d = (_Float16*)carve((size_t)F * 64 * 2);
    _Float16* w2s = (_Float16*)carve((size_t)F * F * 2);
    _Float16* w2d = (_Float16*)carve((size_t)F * F * 2);
    _Float16* w3s = (_Float16*)carve((size_t)F * F * 2);
    _Float16* w3d = (_Float16*)carve((size_t)F * F * 2);
    _Float16* fc1h = (_Float16*)carve((size_t)F * F * 2);
    _Float16* fc2h = (_Float16*)carve((size_t)F * F * 2);
    int* cnt = (int*)carve((size_t)2 * N_NODES * 4);      // [cnt | fill-cursor]
    int* fcnt = cnt + N_NODES;
    int* off = (int*)carve((size_t)(N_NODES + 1) * 4);
    int* csr_e = (int*)carve((size_t)N_EDGES * 4);
    float* part = (float*)carve((size_t)BN_CHUNKS * 2 * F * 4);
    float* scale = (float*)carve(F * 4);
    float* shift = (float*)carve(F * 4);
    int* gstart = (int*)carve((N_GRAPHS + 1) * 4);
    _Float16* hg16 = (_Float16*)carve((size_t)N_GRAPHS * F * 2);
    _Float16* z1h = (_Float16*)carve((size_t)N_GRAPHS * F * 2);
    float* z2 = (float*)carve((size_t)N_GRAPHS * F * 4);
    (void)ws_size;

    // ---- CSR build (deterministic: buckets sorted by edge id) ----
    k_zero_i32<<<(2 * N_NODES + 255) / 256, 256, 0, stream>>>(cnt, 2 * N_NODES);
    k_count<<<(N_EDGES + 255) / 256, 256, 0, stream>>>(dst, cnt);
    k_scan<<<1, 256, 0, stream>>>(cnt, off, gid, gstart);
    k_fill<<<(N_EDGES + 255) / 256, 256, 0, stream>>>(dst, off, fcnt, csr_e);
    k_sort_buckets<<<(N_NODES + 255) / 256, 256, 0, stream>>>(off, csr_e);

    // ---- input conversion + all weight conversions up-front ----
    k_cvt_h<<<(N_PAD * 64 + 255) / 256, 256, 0, stream>>>(h, xh);
    k_zero_pad<<<((N_PAD - N_NODES) * F + 255) / 256, 256, 0, stream>>>(xh);
    k_cvt_w2<<<dim3(2, F / 32, 2), 256, 0, stream>>>(w_src[0], w1s, w_dst[0], w1d, IN_F, 64);
    k_cvt_w6<<<dim3(F / 32, F / 32, 6), 256, 0, stream>>>(
        w_src[1], w2s, w_dst[1], w2d, w_src[2], w3s, w_dst[2], w3d, fc1_w, fc1h, fc2_w, fc2h);

    // ---- 3 GATv2 + BN + lrelu layers ----
    const dim3 ggrid(8, N_PAD / 128);
    const _Float16* ws16[3] = {w1s, w2s, w3s};
    const _Float16* wd16[3] = {w1d, w2d, w3d};
    for (int l = 0; l < 3; ++l) {
        const int Kp = (l == 0) ? 64 : F;
        k_gemm_dual<<<ggrid, 256, 0, stream>>>(xh, ws16[l], wd16[l], b_src[l], b_dst[l],
                                               fs16, fd16, Kp);
        k_gat<<<N_NODES, 128, 0, stream>>>(fs16, fd16, off, csr_e, src, attn[l], bias[l], y16);
        k_bnpart<<<BN_CHUNKS, 256, 0, stream>>>(y16, part);
        k_bnfin<<<F / 256, 256, 0, stream>>>(part, gamma[l], beta[l], scale, shift);
        if (l < 2)
            k_bnapply<<<(N_NODES * (F / 4) + 255) / 256, 256, 0, stream>>>(y16, scale, shift, xh);
    }

    // ---- fused BN+pool + MLP head (MFMA fc1/fc2, wave-reduce fc3) ----
    k_pool_bn<<<dim3(4, N_GRAPHS), 256, 0, stream>>>(y16, scale, shift, gstart, hg16);
    k_mlp_mfma<<<16, 256, 0, stream>>>(hg16, fc1h, fc1_b, z1h, nullptr, 0);
    k_mlp_mfma<<<16, 256, 0, stream>>>(z1h, fc2h, fc2_b, nullptr, z2, 1);
    k_fc3<<<(N_GRAPHS * NCLS * 64 + 255) / 256, 256, 0, stream>>>(z2, fc3_w, fc3_b, (float*)d_out);
}